// Round 18
// baseline (490.232 us; speedup 1.0000x reference)
//
#include <hip/hip_runtime.h>
#include <cstdint>

#define NN 50000
#define NE 800000
#define HD 64
#define ED 16
#define XD 128
#define NL 3
#define NG 64
#define H3 192
#define POOL_SLICES 16

typedef unsigned int uint32;
typedef unsigned short ushort16;

#if __has_builtin(__builtin_amdgcn_fdot2)
#define USE_DOT2 1
typedef _Float16 v2h __attribute__((ext_vector_type(2)));
#else
#define USE_DOT2 0
#endif

static __device__ __forceinline__ float sigm(float x){ return 1.0f/(1.0f+expf(-x)); }

// bf16 helpers (round-to-nearest-even pack)
static __device__ __forceinline__ uint32 f2bf_bits(float f){
  uint32 u = __float_as_uint(f);
  return (u + 0x7fffu + ((u>>16)&1u)) >> 16;
}
static __device__ __forceinline__ uint32 pack2bf(float a, float b){
  return f2bf_bits(a) | (f2bf_bits(b) << 16);
}
static __device__ __forceinline__ float bf_lo(uint32 u){ return __uint_as_float(u << 16); }
static __device__ __forceinline__ float bf_hi(uint32 u){ return __uint_as_float(u & 0xffff0000u); }

#if USE_DOT2
static __device__ __forceinline__ uint32 pack2h(float a, float b){
  v2h p = {(_Float16)a, (_Float16)b};
  return __builtin_bit_cast(uint32, p);
}
static __device__ __forceinline__ float dot2h(uint32 a, uint32 b, float c){
  return __builtin_amdgcn_fdot2(__builtin_bit_cast(v2h, a), __builtin_bit_cast(v2h, b), c, false);
}
#endif

// Shared pre-MLP epilogue: from a wave-local LDS copy of 8 node rows (stride ldh),
// compute m1 = h@W1a + b1 (fp32) and m2 = h@W1b (bf16). No block sync needed.
static __device__ __forceinline__ void pre_from_lds(const float* hW, int ldh,
    const float* __restrict__ w1, const float* __restrict__ b1,
    int nb, int lane, float* __restrict__ m1, ushort16* __restrict__ m2b){
  float a1[8] = {0,0,0,0,0,0,0,0};
  float a2[8] = {0,0,0,0,0,0,0,0};
  #pragma unroll 4
  for (int kq=0;kq<HD/4;kq++){
    float wa[4], wb[4];
    #pragma unroll
    for (int q=0;q<4;q++){
      wa[q] = w1[(kq*4+q)*HD + lane];
      wb[q] = w1[(HD+kq*4+q)*HD + lane];
    }
    #pragma unroll
    for (int n=0;n<8;n++){
      float hk[4];
      *(float4*)hk = *(const float4*)&hW[n*ldh + kq*4];
      #pragma unroll
      for (int q=0;q<4;q++){
        a1[n] = fmaf(hk[q], wa[q], a1[n]);
        a2[n] = fmaf(hk[q], wb[q], a2[n]);
      }
    }
  }
  float bb = b1[lane];
  #pragma unroll
  for (int n=0;n<8;n++){
    m1[(size_t)(nb+n)*HD + lane] = a1[n] + bb;
    m2b[(size_t)(nb+n)*HD + lane] = (ushort16)f2bf_bits(a2[n]);
  }
}

// Fused: h = x@emb_w + emb_b, then layer-0 pre (m1, m2b). Wave handles 8 nodes.
__global__ __launch_bounds__(256) void k_embed_pre(const float* __restrict__ x,
    const float* __restrict__ w, const float* __restrict__ b,
    const float* __restrict__ w1_0, const float* __restrict__ b1_0,
    float* __restrict__ h, float* __restrict__ m1, ushort16* __restrict__ m2b){
  __shared__ float xL[4][8][XD];   // 16 KB
  int w4 = threadIdx.x >> 6, lane = threadIdx.x & 63;
  int nb = blockIdx.x*32 + w4*8;
  if (nb >= NN) return;
  #pragma unroll
  for (int n=0;n<8;n++){
    xL[w4][n][lane]      = x[(size_t)(nb+n)*XD + lane];
    xL[w4][n][64+lane]   = x[(size_t)(nb+n)*XD + 64 + lane];
  }
  float a[8] = {0,0,0,0,0,0,0,0};
  #pragma unroll 4
  for (int kq=0;kq<XD/4;kq++){
    float wv[4];
    #pragma unroll
    for (int q=0;q<4;q++) wv[q] = w[(kq*4+q)*HD + lane];
    #pragma unroll
    for (int n=0;n<8;n++){
      float xk[4];
      *(float4*)xk = *(const float4*)&xL[w4][n][kq*4];
      #pragma unroll
      for (int q=0;q<4;q++) a[n] = fmaf(xk[q], wv[q], a[n]);
    }
  }
  float bb = b[lane];
  #pragma unroll
  for (int n=0;n<8;n++){
    float hv = a[n] + bb;
    h[(size_t)(nb+n)*HD + lane] = hv;
    xL[w4][n][lane] = hv;          // xL fully consumed; reuse first 64 cols as h
  }
  pre_from_lds(&xL[w4][0][0], XD, w1_0, b1_0, nb, lane, m1, m2b);
}

// Standalone pre (layers 1..L-1): h from global, staged in LDS.
__global__ __launch_bounds__(256) void k_pre(const float* __restrict__ h,
    const float* __restrict__ w1, const float* __restrict__ b1,
    float* __restrict__ m1, ushort16* __restrict__ m2b){
  __shared__ float hL[4][8][HD];   // 8 KB
  int w4 = threadIdx.x >> 6, lane = threadIdx.x & 63;
  int nb = blockIdx.x*32 + w4*8;
  if (nb >= NN) return;
  #pragma unroll
  for (int n=0;n<8;n++) hL[w4][n][lane] = h[(size_t)(nb+n)*HD + lane];
  pre_from_lds(&hL[w4][0][0], HD, w1, b1, nb, lane, m1, m2b);
}

__global__ __launch_bounds__(256) void k_degree(const int* __restrict__ row, int* __restrict__ deg){
  int e = blockIdx.x*blockDim.x + threadIdx.x;
  if (e < NE) atomicAdd(&deg[row[e]], 1);
}

// single-block exclusive scan over deg -> row_ptr[N+1], copy to fill_off
__global__ __launch_bounds__(1024) void k_scan(const int* __restrict__ deg,
    int* __restrict__ row_ptr, int* __restrict__ fill_off){
  __shared__ int wsum[16];
  __shared__ int wexcl[16];
  int t = threadIdx.x, lane = t & 63, wid = t >> 6;
  int running = 0;
  for (int base = 0; base < NN; base += 1024){
    int i = base + t;
    int v = (i < NN) ? deg[i] : 0;
    int s = v;
    #pragma unroll
    for (int off=1; off<64; off<<=1){ int u = __shfl_up(s, off); if (lane>=off) s += u; }
    if (lane==63) wsum[wid] = s;
    __syncthreads();
    if (wid==0){
      int ws = (lane<16) ? wsum[lane] : 0;
      #pragma unroll
      for (int off=1; off<16; off<<=1){ int u = __shfl_up(ws, off); if (lane>=off) ws += u; }
      if (lane<16) wexcl[lane] = ws - wsum[lane];
    }
    __syncthreads();
    int excl = running + wexcl[wid] + (s - v);
    if (i < NN){ row_ptr[i] = excl; fill_off[i] = excl; }
    running += wexcl[15] + wsum[15];
    __syncthreads();
  }
  if (t==0) row_ptr[NN] = running;
}

// CSR fill. PERM=1: scatter ONLY eid (4 B/edge) — the 36 B payload moves in
// k_eperm with coalesced writes (R17: payload scatter caused 2.7x write
// amplification, 78 MB for 28.8 MB of data).
template<int PERM>
__global__ __launch_bounds__(256) void k_fill(const int* __restrict__ row, const int* __restrict__ colv,
    int* __restrict__ fill_off, int* __restrict__ col_s, int* __restrict__ eid_s){
  int e = blockIdx.x*blockDim.x + threadIdx.x;
  if (e < NE){
    int r = row[e];
    int p = atomicAdd(&fill_off[r], 1);
    eid_s[p] = e;
    if (!PERM) col_s[p] = colv[e];
  }
}

// Gather pass (PERM only): CSR slot idx coalesced; random full-line reads of
// colv[e] and eattr[e]; coalesced writes of col_s (byte offsets) + f16 eattr_b.
__global__ __launch_bounds__(256) void k_eperm(const int* __restrict__ eid_s,
    const int* __restrict__ colv, const float* __restrict__ eattr,
    int* __restrict__ col_s, ushort16* __restrict__ eattr_b){
  int idx = blockIdx.x*256 + threadIdx.x;
  if (idx >= NE) return;
  int e = eid_s[idx];
  col_s[idx] = colv[e] << 7;   // byte offset: col * HD * 2
  const float4* src = (const float4*)(eattr + (size_t)e*ED);
  float4 s0=src[0], s1=src[1], s2=src[2], s3=src[3];
  uint4 d0, d1;
#if USE_DOT2
  d0.x = pack2h(s0.x,s0.y); d0.y = pack2h(s0.z,s0.w);
  d0.z = pack2h(s1.x,s1.y); d0.w = pack2h(s1.z,s1.w);
  d1.x = pack2h(s2.x,s2.y); d1.y = pack2h(s2.z,s2.w);
  d1.z = pack2h(s3.x,s3.y); d1.w = pack2h(s3.z,s3.w);
#else
  d0.x = pack2bf(s0.x,s0.y); d0.y = pack2bf(s0.z,s0.w);
  d0.z = pack2bf(s1.x,s1.y); d0.w = pack2bf(s1.z,s1.w);
  d1.x = pack2bf(s2.x,s2.y); d1.y = pack2bf(s2.z,s2.w);
  d1.z = pack2bf(s3.x,s3.y); d1.w = pack2bf(s3.z,s3.w);
#endif
  uint4* dst = (uint4*)(eattr_b + (size_t)idx*ED);
  dst[0] = d0; dst[1] = d1;
}

// Fold + pack, GATE-INTERLEAVED layout: WfQ[l][kp][c][4] = {r-pair, z-pair,
// n-pair, pad}, pair packs (k=2kp, k=2kp+1). f16 pairs on the dot2 path (k_gru
// consumes them with v_dot2_f32_f16), bf16 otherwise.
__global__ __launch_bounds__(64) void k_fold(const float* __restrict__ w2, const float* __restrict__ b2,
    const float* __restrict__ wih, const float* __restrict__ whh,
    uint32* __restrict__ WfQ, uint32* __restrict__ WhQ, float* __restrict__ bv){
  int bid = blockIdx.x;
  int l = bid / H3, i = bid % H3;
  int k = threadIdx.x;
  const float* w2l  = w2  + (size_t)l*HD*HD;
  const float* wihl = wih + (size_t)l*H3*HD;
  const float* whhl = whh + (size_t)l*H3*HD;
  float acc = 0.f;
  #pragma unroll 8
  for (int m=0;m<HD;m++) acc = fmaf(w2l[k*HD+m], wihl[i*HD+m], acc);
  float wh = whhl[(size_t)i*HD + k];
  float accN = __shfl_down(acc, 1);
  float whN  = __shfl_down(wh, 1);
  if ((k & 1) == 0){
    int g = i >> 6, c = i & 63;
    size_t base = (((size_t)l*32 + (k>>1))*64 + c)*4 + g;
#if USE_DOT2
    WfQ[base] = pack2h(acc, accN);
    WhQ[base] = pack2h(wh, whN);
#else
    WfQ[base] = pack2bf(acc, accN);
    WhQ[base] = pack2bf(wh, whN);
#endif
  }
  if (k==0){
    float a = 0.f;
    const float* b2l = b2 + l*HD;
    for (int m=0;m<HD;m++) a = fmaf(b2l[m], wihl[i*HD+m], a);
    bv[l*H3 + i] = a;
  }
}

#if USE_DOT2
// 16 f16 eattr values (2 uint4) folded into t via 8 v_dot2_f32_f16
static __device__ __forceinline__ float edge_term(uint4 ua, uint4 ub, const uint32* wch, float t){
  t = dot2h(ua.x, wch[0], t); t = dot2h(ua.y, wch[1], t);
  t = dot2h(ua.z, wch[2], t); t = dot2h(ua.w, wch[3], t);
  t = dot2h(ub.x, wch[4], t); t = dot2h(ub.y, wch[5], t);
  t = dot2h(ub.z, wch[6], t); t = dot2h(ub.w, wch[7], t);
  return t;
}
#else
static __device__ __forceinline__ float edge_term(uint4 ua, uint4 ub, const float* wch, float t){
  uint32 us[8] = {ua.x,ua.y,ua.z,ua.w,ub.x,ub.y,ub.z,ub.w};
  #pragma unroll
  for (int k=0;k<8;k++){
    t = fmaf(bf_lo(us[k]), wch[2*k],   t);
    t = fmaf(bf_hi(us[k]), wch[2*k+1], t);
  }
  return t;
}
#endif

// tsum[n] = sum over CSR edges of relu(m1[n] + m2[col] + eattr[e]@W1c).
// SCALARIZED row (R11 win): wid/row_ptr/col_s/eattr_b wave-uniform -> SMEM path.
template<int PERM>
__global__ __launch_bounds__(256) void k_agg(const float* __restrict__ m1, const ushort16* __restrict__ m2b,
    const float* __restrict__ eattr, const ushort16* __restrict__ eattr_b, const float* __restrict__ w1c,
    const int* __restrict__ row_ptr, const int* __restrict__ col_s, const int* __restrict__ eid_s,
    float* __restrict__ tsum){
  int lane = threadIdx.x & 63;
  int wid_v = blockIdx.x*4 + (threadIdx.x>>6);
  int wid = __builtin_amdgcn_readfirstlane(wid_v);
  if (wid >= NN) return;
  float base = m1[(size_t)wid*HD + lane];
  int s     = __builtin_amdgcn_readfirstlane(row_ptr[wid]);
  int e_end = __builtin_amdgcn_readfirstlane(row_ptr[wid+1]);
  float ts0=0.f, ts1=0.f, ts2=0.f, ts3=0.f;
  int idx = s;
  if (PERM){
    const char* mb = (const char*)m2b;
    uint32 l2 = (uint32)lane * 2u;
#if USE_DOT2
    uint32 wch[8];
    #pragma unroll
    for (int k=0;k<8;k++) wch[k] = pack2h(w1c[(2*k)*HD + lane], w1c[(2*k+1)*HD + lane]);
#else
    float wch[ED];
    #pragma unroll
    for (int k=0;k<ED;k++) wch[k] = w1c[k*HD + lane];
#endif
    for (; idx + 8 <= e_end; idx += 8){
      int c0 = col_s[idx+0], c1 = col_s[idx+1], c2 = col_s[idx+2], c3 = col_s[idx+3];
      int c4 = col_s[idx+4], c5 = col_s[idx+5], c6 = col_s[idx+6], c7 = col_s[idx+7];
      unsigned short g0 = *(const unsigned short*)(mb + (uint32)c0 + l2);
      unsigned short g1 = *(const unsigned short*)(mb + (uint32)c1 + l2);
      unsigned short g2 = *(const unsigned short*)(mb + (uint32)c2 + l2);
      unsigned short g3 = *(const unsigned short*)(mb + (uint32)c3 + l2);
      unsigned short g4 = *(const unsigned short*)(mb + (uint32)c4 + l2);
      unsigned short g5 = *(const unsigned short*)(mb + (uint32)c5 + l2);
      unsigned short g6 = *(const unsigned short*)(mb + (uint32)c6 + l2);
      unsigned short g7 = *(const unsigned short*)(mb + (uint32)c7 + l2);
      const uint4* ea = (const uint4*)(eattr_b + (size_t)idx*ED);
      uint4 e0=ea[0],  e1=ea[1],  e2=ea[2],  e3=ea[3];
      uint4 e4=ea[4],  e5=ea[5],  e6=ea[6],  e7=ea[7];
      uint4 e8=ea[8],  e9=ea[9],  e10=ea[10],e11=ea[11];
      uint4 e12=ea[12],e13=ea[13],e14=ea[14],e15=ea[15];
      ts0 += fmaxf(edge_term(e0,  e1,  wch, base + bf_lo(g0)), 0.f);
      ts1 += fmaxf(edge_term(e2,  e3,  wch, base + bf_lo(g1)), 0.f);
      ts2 += fmaxf(edge_term(e4,  e5,  wch, base + bf_lo(g2)), 0.f);
      ts3 += fmaxf(edge_term(e6,  e7,  wch, base + bf_lo(g3)), 0.f);
      ts0 += fmaxf(edge_term(e8,  e9,  wch, base + bf_lo(g4)), 0.f);
      ts1 += fmaxf(edge_term(e10, e11, wch, base + bf_lo(g5)), 0.f);
      ts2 += fmaxf(edge_term(e12, e13, wch, base + bf_lo(g6)), 0.f);
      ts3 += fmaxf(edge_term(e14, e15, wch, base + bf_lo(g7)), 0.f);
    }
    if (idx + 4 <= e_end){
      int c0 = col_s[idx+0], c1 = col_s[idx+1], c2 = col_s[idx+2], c3 = col_s[idx+3];
      unsigned short g0 = *(const unsigned short*)(mb + (uint32)c0 + l2);
      unsigned short g1 = *(const unsigned short*)(mb + (uint32)c1 + l2);
      unsigned short g2 = *(const unsigned short*)(mb + (uint32)c2 + l2);
      unsigned short g3 = *(const unsigned short*)(mb + (uint32)c3 + l2);
      const uint4* ea = (const uint4*)(eattr_b + (size_t)idx*ED);
      uint4 e0=ea[0], e1=ea[1], e2=ea[2], e3=ea[3];
      uint4 e4=ea[4], e5=ea[5], e6=ea[6], e7=ea[7];
      ts0 += fmaxf(edge_term(e0, e1, wch, base + bf_lo(g0)), 0.f);
      ts1 += fmaxf(edge_term(e2, e3, wch, base + bf_lo(g1)), 0.f);
      ts2 += fmaxf(edge_term(e4, e5, wch, base + bf_lo(g2)), 0.f);
      ts3 += fmaxf(edge_term(e6, e7, wch, base + bf_lo(g3)), 0.f);
      idx += 4;
    }
    for (; idx < e_end; idx++){
      int c = col_s[idx];
      unsigned short g = *(const unsigned short*)(mb + (uint32)c + l2);
      const uint4* ea = (const uint4*)(eattr_b + (size_t)idx*ED);
      uint4 e0 = ea[0], e1 = ea[1];
      ts0 += fmaxf(edge_term(e0, e1, wch, base + bf_lo(g)), 0.f);
    }
  } else {
    float wc[ED];
    #pragma unroll
    for (int k=0;k<ED;k++) wc[k] = w1c[k*HD + lane];
    for (; idx < e_end; idx++){
      int c = col_s[idx];
      int e = eid_s[idx];
      const float4* ea4 = (const float4*)(eattr + (size_t)e*ED);
      float4 a0 = ea4[0], a1 = ea4[1], a2 = ea4[2], a3 = ea4[3];
      float t = base + bf_lo((uint32)m2b[(size_t)c*HD + lane]);
      t = fmaf(a0.x, wc[0],  t); t = fmaf(a0.y, wc[1],  t);
      t = fmaf(a0.z, wc[2],  t); t = fmaf(a0.w, wc[3],  t);
      t = fmaf(a1.x, wc[4],  t); t = fmaf(a1.y, wc[5],  t);
      t = fmaf(a1.z, wc[6],  t); t = fmaf(a1.w, wc[7],  t);
      t = fmaf(a2.x, wc[8],  t); t = fmaf(a2.y, wc[9],  t);
      t = fmaf(a2.z, wc[10], t); t = fmaf(a2.w, wc[11], t);
      t = fmaf(a3.x, wc[12], t); t = fmaf(a3.y, wc[13], t);
      t = fmaf(a3.z, wc[14], t); t = fmaf(a3.w, wc[15], t);
      ts0 += fmaxf(t, 0.f);
    }
  }
  tsum[(size_t)wid*HD + lane] = (ts0 + ts1) + (ts2 + ts3);
}

#if USE_DOT2
// GRU, 8 nodes/wave, dot2 inner loop (verified R17): acts f16-packed in
// wave-private LDS, weights f16-packed gate-interleaved uint4.
__global__ __launch_bounds__(256) void k_gru(float* __restrict__ h, const float* __restrict__ tsum,
    const int* __restrict__ row_ptr,
    const uint32* __restrict__ WfQ, const uint32* __restrict__ WhQ,
    const float* __restrict__ bv, const float* __restrict__ bih, const float* __restrict__ bhh){
  __shared__ uint32 tsP[4][8][32];  // 4 KB
  __shared__ uint32 hP[4][8][32];   // 4 KB
  int w4 = threadIdx.x >> 6, lane = threadIdx.x & 63;
  int nb = blockIdx.x*32 + w4*8;
  if (nb >= NN) return;
  {
    int n = lane>>3, j = lane&7;
    const float4* t4 = (const float4*)(tsum + (size_t)(nb+n)*HD + j*8);
    float4 a0=t4[0], a1=t4[1];
    uint4 pt;
    pt.x=pack2h(a0.x,a0.y); pt.y=pack2h(a0.z,a0.w); pt.z=pack2h(a1.x,a1.y); pt.w=pack2h(a1.z,a1.w);
    *(uint4*)&tsP[w4][n][j*4] = pt;
    const float4* g4 = (const float4*)(h + (size_t)(nb+n)*HD + j*8);
    float4 b0=g4[0], b1=g4[1];
    uint4 ph;
    ph.x=pack2h(b0.x,b0.y); ph.y=pack2h(b0.z,b0.w); ph.z=pack2h(b1.x,b1.y); ph.w=pack2h(b1.z,b1.w);
    *(uint4*)&hP[w4][n][j*4] = ph;
  }
  const uint4* fq = (const uint4*)WfQ;
  const uint4* hq = (const uint4*)WhQ;
  float gr[8]={0,0,0,0,0,0,0,0}, gz[8]={0,0,0,0,0,0,0,0}, gn[8]={0,0,0,0,0,0,0,0};
  float pr[8]={0,0,0,0,0,0,0,0}, pz[8]={0,0,0,0,0,0,0,0}, pn[8]={0,0,0,0,0,0,0,0};
  #pragma unroll 2
  for (int kq=0;kq<HD/4;kq++){
    uint4 f0 = fq[(2*kq)*64 + lane];
    uint4 f1 = fq[(2*kq+1)*64 + lane];
    uint4 h0 = hq[(2*kq)*64 + lane];
    uint4 h1 = hq[(2*kq+1)*64 + lane];
    #pragma unroll
    for (int n=0;n<8;n++){
      uint32 ta0 = tsP[w4][n][2*kq], ta1 = tsP[w4][n][2*kq+1];
      uint32 hb0 = hP[w4][n][2*kq],  hb1 = hP[w4][n][2*kq+1];
      gr[n]=dot2h(ta0,f0.x,gr[n]); gr[n]=dot2h(ta1,f1.x,gr[n]);
      gz[n]=dot2h(ta0,f0.y,gz[n]); gz[n]=dot2h(ta1,f1.y,gz[n]);
      gn[n]=dot2h(ta0,f0.z,gn[n]); gn[n]=dot2h(ta1,f1.z,gn[n]);
      pr[n]=dot2h(hb0,h0.x,pr[n]); pr[n]=dot2h(hb1,h1.x,pr[n]);
      pz[n]=dot2h(hb0,h0.y,pz[n]); pz[n]=dot2h(hb1,h1.y,pz[n]);
      pn[n]=dot2h(hb0,h0.z,pn[n]); pn[n]=dot2h(hb1,h1.z,pn[n]);
    }
  }
  float bvr=bv[lane], bvz=bv[HD+lane], bvn=bv[2*HD+lane];
  float bir=bih[lane], biz=bih[HD+lane], bin=bih[2*HD+lane];
  float bhr=bhh[lane], bhz=bhh[HD+lane], bhn=bhh[2*HD+lane];
  int rp0 = row_ptr[nb];
  #pragma unroll
  for (int n=0;n<8;n++){
    int rp1 = row_ptr[nb+n+1];
    float deg = (float)(rp1 - rp0);
    rp0 = rp1;
    float r  = sigm(gr[n]+pr[n] + deg*bvr + bir + bhr);
    float z  = sigm(gz[n]+pz[n] + deg*bvz + biz + bhz);
    // torch GRU: n = tanh(gi_n + r*gh_n); gi_n = gn + deg*bvn + bin; gh_n = pn + bhn
    float nv = tanhf(gn[n] + deg*bvn + bin + r*(pn[n] + bhn));
    float hv = h[(size_t)(nb+n)*HD + lane];   // exact fp32 h for the blend (L2-hot)
    h[(size_t)(nb+n)*HD + lane] = (1.f - z)*nv + z*hv;
  }
}
#else
// bf16-unpack fallback (verified R16 structure).
__global__ __launch_bounds__(256) void k_gru(float* __restrict__ h, const float* __restrict__ tsum,
    const int* __restrict__ row_ptr,
    const uint32* __restrict__ WfQ, const uint32* __restrict__ WhQ,
    const float* __restrict__ bv, const float* __restrict__ bih, const float* __restrict__ bhh){
  __shared__ float tsL[4][8][HD];
  __shared__ float hL[4][8][HD];
  int w4 = threadIdx.x >> 6, lane = threadIdx.x & 63;
  int nb = blockIdx.x*32 + w4*8;
  if (nb >= NN) return;
  #pragma unroll
  for (int n=0;n<8;n++){
    tsL[w4][n][lane] = tsum[(size_t)(nb+n)*HD + lane];
    hL[w4][n][lane]  = h[(size_t)(nb+n)*HD + lane];
  }
  const uint4* fq = (const uint4*)WfQ;
  const uint4* hq = (const uint4*)WhQ;
  float gr[8]={0,0,0,0,0,0,0,0}, gz[8]={0,0,0,0,0,0,0,0}, gn[8]={0,0,0,0,0,0,0,0};
  float pr[8]={0,0,0,0,0,0,0,0}, pz[8]={0,0,0,0,0,0,0,0}, pn[8]={0,0,0,0,0,0,0,0};
  #pragma unroll 2
  for (int kq=0;kq<HD/4;kq++){
    uint4 f0 = fq[(2*kq)*64 + lane];
    uint4 f1 = fq[(2*kq+1)*64 + lane];
    uint4 h0 = hq[(2*kq)*64 + lane];
    uint4 h1 = hq[(2*kq+1)*64 + lane];
    float wfr[4]={bf_lo(f0.x),bf_hi(f0.x),bf_lo(f1.x),bf_hi(f1.x)};
    float wfz[4]={bf_lo(f0.y),bf_hi(f0.y),bf_lo(f1.y),bf_hi(f1.y)};
    float wfn[4]={bf_lo(f0.z),bf_hi(f0.z),bf_lo(f1.z),bf_hi(f1.z)};
    float whr[4]={bf_lo(h0.x),bf_hi(h0.x),bf_lo(h1.x),bf_hi(h1.x)};
    float whz[4]={bf_lo(h0.y),bf_hi(h0.y),bf_lo(h1.y),bf_hi(h1.y)};
    float whn[4]={bf_lo(h0.z),bf_hi(h0.z),bf_lo(h1.z),bf_hi(h1.z)};
    #pragma unroll
    for (int n=0;n<8;n++){
      float tk[4], hk[4];
      *(float4*)tk = *(const float4*)&tsL[w4][n][kq*4];
      *(float4*)hk = *(const float4*)&hL[w4][n][kq*4];
      #pragma unroll
      for (int q=0;q<4;q++){
        gr[n]=fmaf(tk[q],wfr[q],gr[n]); gz[n]=fmaf(tk[q],wfz[q],gz[n]); gn[n]=fmaf(tk[q],wfn[q],gn[n]);
        pr[n]=fmaf(hk[q],whr[q],pr[n]); pz[n]=fmaf(hk[q],whz[q],pz[n]); pn[n]=fmaf(hk[q],whn[q],pn[n]);
      }
    }
  }
  float bvr=bv[lane], bvz=bv[HD+lane], bvn=bv[2*HD+lane];
  float bir=bih[lane], biz=bih[HD+lane], bin=bih[2*HD+lane];
  float bhr=bhh[lane], bhz=bhh[HD+lane], bhn=bhh[2*HD+lane];
  int rp0 = row_ptr[nb];
  #pragma unroll
  for (int n=0;n<8;n++){
    int rp1 = row_ptr[nb+n+1];
    float deg = (float)(rp1 - rp0);
    rp0 = rp1;
    float r  = sigm(gr[n]+pr[n] + deg*bvr + bir + bhr);
    float z  = sigm(gz[n]+pz[n] + deg*bvz + biz + bhz);
    float nv = tanhf(gn[n] + deg*bvn + bin + r*(pn[n] + bhn));
    float hv = hL[w4][n][lane];
    h[(size_t)(nb+n)*HD + lane] = (1.f - z)*nv + z*hv;
  }
}
#endif

// Graph-centric mean pool.
__global__ __launch_bounds__(256) void k_pool(const float* __restrict__ h, const int* __restrict__ batch,
    float* __restrict__ gsum, float* __restrict__ gcnt){
  __shared__ int rng[2];
  __shared__ float red[4][HD];
  int g = blockIdx.x / POOL_SLICES;
  int slice = blockIdx.x % POOL_SLICES;
  int t = threadIdx.x, lane = t & 63, w = t >> 6;
  if (t < 2){
    int target = g + t;
    int lo = 0, hi = NN;
    while (lo < hi){ int mid = (lo + hi) >> 1; if (batch[mid] < target) lo = mid + 1; else hi = mid; }
    rng[t] = lo;
  }
  __syncthreads();
  int start = rng[0], end = rng[1];
  if (slice == 0 && t == 0) gcnt[g] = (float)(end - start);
  int len = end - start;
  int per = (len + POOL_SLICES - 1) / POOL_SLICES;
  int s0 = start + slice * per;
  int s1 = min(s0 + per, end);
  float acc = 0.f;
  for (int n = s0 + w; n < s1; n += 4) acc += h[(size_t)n*HD + lane];
  red[w][lane] = acc;
  __syncthreads();
  if (w == 0){
    float v = red[0][lane] + red[1][lane] + red[2][lane] + red[3][lane];
    atomicAdd(&gsum[g*HD + lane], v);
  }
}

__global__ __launch_bounds__(64) void k_readout(const float* __restrict__ gsum, const float* __restrict__ gcnt,
    const float* __restrict__ w1, const float* __restrict__ b1,
    const float* __restrict__ w2, const float* __restrict__ b2, float* __restrict__ out){
  int g = blockIdx.x;
  int lane = threadIdx.x;
  float c = fmaxf(gcnt[g], 1.0f);
  float gm = gsum[g*HD + lane] / c;
  float a = b1[lane];
  for (int k=0;k<HD;k++) a = fmaf(__shfl(gm, k), w1[k*HD + lane], a);
  a = fmaxf(a, 0.f);
  float p = a * w2[lane];
  #pragma unroll
  for (int off=32; off>0; off>>=1) p += __shfl_down(p, off);
  if (lane==0) out[g] = 1.f/(1.f + expf(-(p + b2[0])));
}

extern "C" void kernel_launch(void* const* d_in, const int* in_sizes, int n_in,
                              void* d_out, int out_size, void* d_ws, size_t ws_size,
                              hipStream_t stream){
  const float* x        = (const float*)d_in[0];
  const int*   eidx     = (const int*)d_in[1];
  const float* eattr    = (const float*)d_in[2];
  const int*   batch    = (const int*)d_in[3];
  const float* emb_w    = (const float*)d_in[4];
  const float* emb_b    = (const float*)d_in[5];
  const float* msg_w1   = (const float*)d_in[6];
  const float* msg_b1   = (const float*)d_in[7];
  const float* msg_w2   = (const float*)d_in[8];
  const float* msg_b2   = (const float*)d_in[9];
  const float* gru_wih  = (const float*)d_in[10];
  const float* gru_whh  = (const float*)d_in[11];
  const float* gru_bih  = (const float*)d_in[12];
  const float* gru_bhh  = (const float*)d_in[13];
  const float* ro_w1    = (const float*)d_in[14];
  const float* ro_b1    = (const float*)d_in[15];
  const float* ro_w2    = (const float*)d_in[16];
  const float* ro_b2    = (const float*)d_in[17];
  float* out = (float*)d_out;

  char* p = (char*)d_ws;
  size_t used = 0;
  auto alloc = [&](size_t bytes)->void*{
    void* r = (void*)p; size_t rb = (bytes + 255) & ~(size_t)255; p += rb; used += rb; return r;
  };
  float*     h    = (float*)alloc((size_t)NN*HD*4);
  float*     m1   = (float*)alloc((size_t)NN*HD*4);
  ushort16*  m2b  = (ushort16*)alloc((size_t)NN*HD*2);
  float*     tsum = (float*)alloc((size_t)NN*HD*4);
  int*       deg  = (int*)  alloc((size_t)NN*4);
  int*       rowp = (int*)  alloc((size_t)(NN+1)*4);
  int*       foff = (int*)  alloc((size_t)NN*4);
  int*       col_s= (int*)  alloc((size_t)NE*4);
  int*       eid_s= (int*)  alloc((size_t)NE*4);
  uint32*    WfQ  = (uint32*)alloc((size_t)NL*32*64*4*4);  // gate-interleaved
  uint32*    WhQ  = (uint32*)alloc((size_t)NL*32*64*4*4);
  float*     bv   = (float*)alloc((size_t)NL*H3*4);
  float*     gsum = (float*)alloc((size_t)NG*HD*4);
  float*     gcnt = (float*)alloc((size_t)NG*4);
  // permuted f16/bf16 edge_attr (25.6 MB) — only if workspace allows
  size_t ea_bytes = (size_t)NE*ED*2;
  bool perm = (used + ea_bytes + 256) <= ws_size;
  ushort16* eattr_b = perm ? (ushort16*)alloc(ea_bytes) : nullptr;

  const int* row = eidx;
  const int* col = eidx + NE;

  hipMemsetAsync(deg,  0, (size_t)NN*4, stream);
  hipMemsetAsync(gsum, 0, (size_t)NG*HD*4, stream);

  const int nb32 = (NN + 31)/32;       // 8 nodes/wave, 4 waves/block
  const int nbw  = (NN + 3)/4;         // 1 node/wave (k_agg)
  const int nbe  = (NE + 255)/256;

  k_degree<<<nbe, 256, 0, stream>>>(row, deg);
  k_scan  <<<1, 1024, 0, stream>>>(deg, rowp, foff);
  if (perm){
    k_fill<1><<<nbe, 256, 0, stream>>>(row, col, foff, col_s, eid_s);
    k_eperm  <<<nbe, 256, 0, stream>>>(eid_s, col, eattr, col_s, eattr_b);
  } else {
    k_fill<0><<<nbe, 256, 0, stream>>>(row, col, foff, col_s, eid_s);
  }
  k_fold  <<<NL*H3, 64, 0, stream>>>(msg_w2, msg_b2, gru_wih, gru_whh, WfQ, WhQ, bv);
  k_embed_pre<<<nb32, 256, 0, stream>>>(x, emb_w, emb_b, msg_w1, msg_b1, h, m1, m2b);

  for (int l=0; l<NL; l++){
    const float* w1l = msg_w1 + (size_t)l*(2*HD+ED)*HD;
    if (l > 0){
      k_pre<<<nb32, 256, 0, stream>>>(h, w1l, msg_b1 + l*HD, m1, m2b);
    }
    if (perm) k_agg<1><<<nbw, 256, 0, stream>>>(m1, m2b, eattr, eattr_b, w1l + (size_t)2*HD*HD,
                                                rowp, col_s, eid_s, tsum);
    else      k_agg<0><<<nbw, 256, 0, stream>>>(m1, m2b, eattr, eattr_b, w1l + (size_t)2*HD*HD,
                                                rowp, col_s, eid_s, tsum);
    k_gru<<<nb32, 256, 0, stream>>>(h, tsum, rowp,
                                    WfQ + (size_t)l*32*64*4, WhQ + (size_t)l*32*64*4,
                                    bv + l*H3, gru_bih + l*H3, gru_bhh + l*H3);
  }

  k_pool   <<<NG*POOL_SLICES, 256, 0, stream>>>(h, batch, gsum, gcnt);
  k_readout<<<NG, 64, 0, stream>>>(gsum, gcnt, ro_w1, ro_b1, ro_w2, ro_b2, out);
}

// Round 19
// 436.637 us; speedup vs baseline: 1.1227x; 1.1227x over previous
//
#include <hip/hip_runtime.h>
#include <cstdint>

#define NN 50000
#define NE 800000
#define HD 64
#define ED 16
#define XD 128
#define NL 3
#define NG 64
#define H3 192
#define POOL_SLICES 16

typedef unsigned int uint32;
typedef unsigned short ushort16;

#if __has_builtin(__builtin_amdgcn_fdot2)
#define USE_DOT2 1
typedef _Float16 v2h __attribute__((ext_vector_type(2)));
#else
#define USE_DOT2 0
#endif

static __device__ __forceinline__ float sigm(float x){ return 1.0f/(1.0f+expf(-x)); }

static __device__ __forceinline__ uint32 f2bf_bits(float f){
  uint32 u = __float_as_uint(f);
  return (u + 0x7fffu + ((u>>16)&1u)) >> 16;
}
static __device__ __forceinline__ uint32 pack2bf(float a, float b){
  return f2bf_bits(a) | (f2bf_bits(b) << 16);
}
static __device__ __forceinline__ float bf_lo(uint32 u){ return __uint_as_float(u << 16); }
static __device__ __forceinline__ float bf_hi(uint32 u){ return __uint_as_float(u & 0xffff0000u); }

#if USE_DOT2
static __device__ __forceinline__ uint32 pack2h(float a, float b){
  v2h p = {(_Float16)a, (_Float16)b};
  return __builtin_bit_cast(uint32, p);
}
static __device__ __forceinline__ float dot2h(uint32 a, uint32 b, float c){
  return __builtin_amdgcn_fdot2(__builtin_bit_cast(v2h, a), __builtin_bit_cast(v2h, b), c, false);
}
#endif

// Shared pre-MLP epilogue: from a wave-local LDS copy of 8 node rows (stride ldh),
// compute m1 = h@W1a + b1 (fp32) and m2 = h@W1b (bf16). No block sync needed.
static __device__ __forceinline__ void pre_from_lds(const float* hW, int ldh,
    const float* __restrict__ w1, const float* __restrict__ b1,
    int nb, int lane, float* __restrict__ m1, ushort16* __restrict__ m2b){
  float a1[8] = {0,0,0,0,0,0,0,0};
  float a2[8] = {0,0,0,0,0,0,0,0};
  #pragma unroll 4
  for (int kq=0;kq<HD/4;kq++){
    float wa[4], wb[4];
    #pragma unroll
    for (int q=0;q<4;q++){
      wa[q] = w1[(kq*4+q)*HD + lane];
      wb[q] = w1[(HD+kq*4+q)*HD + lane];
    }
    #pragma unroll
    for (int n=0;n<8;n++){
      float hk[4];
      *(float4*)hk = *(const float4*)&hW[n*ldh + kq*4];
      #pragma unroll
      for (int q=0;q<4;q++){
        a1[n] = fmaf(hk[q], wa[q], a1[n]);
        a2[n] = fmaf(hk[q], wb[q], a2[n]);
      }
    }
  }
  float bb = b1[lane];
  #pragma unroll
  for (int n=0;n<8;n++){
    m1[(size_t)(nb+n)*HD + lane] = a1[n] + bb;
    m2b[(size_t)(nb+n)*HD + lane] = (ushort16)f2bf_bits(a2[n]);
  }
}

// Fused: h = x@emb_w + emb_b, then layer-0 pre (m1, m2b). Wave handles 8 nodes.
__global__ __launch_bounds__(256) void k_embed_pre(const float* __restrict__ x,
    const float* __restrict__ w, const float* __restrict__ b,
    const float* __restrict__ w1_0, const float* __restrict__ b1_0,
    float* __restrict__ h, float* __restrict__ m1, ushort16* __restrict__ m2b){
  __shared__ float xL[4][8][XD];   // 16 KB
  int w4 = threadIdx.x >> 6, lane = threadIdx.x & 63;
  int nb = blockIdx.x*32 + w4*8;
  if (nb >= NN) return;
  #pragma unroll
  for (int n=0;n<8;n++){
    xL[w4][n][lane]      = x[(size_t)(nb+n)*XD + lane];
    xL[w4][n][64+lane]   = x[(size_t)(nb+n)*XD + 64 + lane];
  }
  float a[8] = {0,0,0,0,0,0,0,0};
  #pragma unroll 4
  for (int kq=0;kq<XD/4;kq++){
    float wv[4];
    #pragma unroll
    for (int q=0;q<4;q++) wv[q] = w[(kq*4+q)*HD + lane];
    #pragma unroll
    for (int n=0;n<8;n++){
      float xk[4];
      *(float4*)xk = *(const float4*)&xL[w4][n][kq*4];
      #pragma unroll
      for (int q=0;q<4;q++) a[n] = fmaf(xk[q], wv[q], a[n]);
    }
  }
  float bb = b[lane];
  #pragma unroll
  for (int n=0;n<8;n++){
    float hv = a[n] + bb;
    h[(size_t)(nb+n)*HD + lane] = hv;
    xL[w4][n][lane] = hv;          // xL fully consumed; reuse first 64 cols as h
  }
  pre_from_lds(&xL[w4][0][0], XD, w1_0, b1_0, nb, lane, m1, m2b);
}

// Standalone pre (layers 1..L-1): h from global, staged in LDS.
__global__ __launch_bounds__(256) void k_pre(const float* __restrict__ h,
    const float* __restrict__ w1, const float* __restrict__ b1,
    float* __restrict__ m1, ushort16* __restrict__ m2b){
  __shared__ float hL[4][8][HD];   // 8 KB
  int w4 = threadIdx.x >> 6, lane = threadIdx.x & 63;
  int nb = blockIdx.x*32 + w4*8;
  if (nb >= NN) return;
  #pragma unroll
  for (int n=0;n<8;n++) hL[w4][n][lane] = h[(size_t)(nb+n)*HD + lane];
  pre_from_lds(&hL[w4][0][0], HD, w1, b1, nb, lane, m1, m2b);
}

// Degree + per-edge rank (coalesced 4B write by e): rank[e] = old count.
__global__ __launch_bounds__(256) void k_degree(const int* __restrict__ row,
    int* __restrict__ deg, int* __restrict__ rank){
  int e = blockIdx.x*blockDim.x + threadIdx.x;
  if (e < NE) rank[e] = atomicAdd(&deg[row[e]], 1);
}

// single-block exclusive scan over deg -> row_ptr[N+1]
__global__ __launch_bounds__(1024) void k_scan(const int* __restrict__ deg,
    int* __restrict__ row_ptr){
  __shared__ int wsum[16];
  __shared__ int wexcl[16];
  int t = threadIdx.x, lane = t & 63, wid = t >> 6;
  int running = 0;
  for (int base = 0; base < NN; base += 1024){
    int i = base + t;
    int v = (i < NN) ? deg[i] : 0;
    int s = v;
    #pragma unroll
    for (int off=1; off<64; off<<=1){ int u = __shfl_up(s, off); if (lane>=off) s += u; }
    if (lane==63) wsum[wid] = s;
    __syncthreads();
    if (wid==0){
      int ws = (lane<16) ? wsum[lane] : 0;
      #pragma unroll
      for (int off=1; off<16; off<<=1){ int u = __shfl_up(ws, off); if (lane>=off) ws += u; }
      if (lane<16) wexcl[lane] = ws - wsum[lane];
    }
    __syncthreads();
    int excl = running + wexcl[wid] + (s - v);
    if (i < NN) row_ptr[i] = excl;
    running += wexcl[15] + wsum[15];
    __syncthreads();
  }
  if (t==0) row_ptr[NN] = running;
}

// CSR fill, ATOMIC-FREE: p = row_ptr[row[e]] + rank[e] (plain loads). Scatter
// the full payload in one pass (R18 lesson: write amplification is 64B-line-
// granular, so splitting the payload buys nothing — one pass is optimal).
template<int PERM>
__global__ __launch_bounds__(256) void k_fill(const int* __restrict__ row, const int* __restrict__ colv,
    const int* __restrict__ row_ptr, const int* __restrict__ rank,
    const float* __restrict__ eattr,
    int* __restrict__ col_s, int* __restrict__ eid_s,
    ushort16* __restrict__ eattr_b){
  int e = blockIdx.x*blockDim.x + threadIdx.x;
  if (e < NE){
    int r = row[e];
    int p = row_ptr[r] + rank[e];
    if (PERM){
      col_s[p] = colv[e] << 7;   // byte offset: col * HD * 2
      const float4* src = (const float4*)(eattr + (size_t)e*ED);
      float4 s0=src[0], s1=src[1], s2=src[2], s3=src[3];
      uint4 d0, d1;
#if USE_DOT2
      d0.x = pack2h(s0.x,s0.y); d0.y = pack2h(s0.z,s0.w);
      d0.z = pack2h(s1.x,s1.y); d0.w = pack2h(s1.z,s1.w);
      d1.x = pack2h(s2.x,s2.y); d1.y = pack2h(s2.z,s2.w);
      d1.z = pack2h(s3.x,s3.y); d1.w = pack2h(s3.z,s3.w);
#else
      d0.x = pack2bf(s0.x,s0.y); d0.y = pack2bf(s0.z,s0.w);
      d0.z = pack2bf(s1.x,s1.y); d0.w = pack2bf(s1.z,s1.w);
      d1.x = pack2bf(s2.x,s2.y); d1.y = pack2bf(s2.z,s2.w);
      d1.z = pack2bf(s3.x,s3.y); d1.w = pack2bf(s3.z,s3.w);
#endif
      uint4* dst = (uint4*)(eattr_b + (size_t)p*ED);
      dst[0] = d0; dst[1] = d1;
    } else {
      col_s[p] = colv[e];
      eid_s[p] = e;
    }
  }
}

// Fold + pack, GATE-INTERLEAVED layout: WfQ[l][kp][c][4] = {r-pair, z-pair,
// n-pair, pad}, pair packs (k=2kp, k=2kp+1). f16 pairs on the dot2 path.
__global__ __launch_bounds__(64) void k_fold(const float* __restrict__ w2, const float* __restrict__ b2,
    const float* __restrict__ wih, const float* __restrict__ whh,
    uint32* __restrict__ WfQ, uint32* __restrict__ WhQ, float* __restrict__ bv){
  int bid = blockIdx.x;
  int l = bid / H3, i = bid % H3;
  int k = threadIdx.x;
  const float* w2l  = w2  + (size_t)l*HD*HD;
  const float* wihl = wih + (size_t)l*H3*HD;
  const float* whhl = whh + (size_t)l*H3*HD;
  float acc = 0.f;
  #pragma unroll 8
  for (int m=0;m<HD;m++) acc = fmaf(w2l[k*HD+m], wihl[i*HD+m], acc);
  float wh = whhl[(size_t)i*HD + k];
  float accN = __shfl_down(acc, 1);
  float whN  = __shfl_down(wh, 1);
  if ((k & 1) == 0){
    int g = i >> 6, c = i & 63;
    size_t base = (((size_t)l*32 + (k>>1))*64 + c)*4 + g;
#if USE_DOT2
    WfQ[base] = pack2h(acc, accN);
    WhQ[base] = pack2h(wh, whN);
#else
    WfQ[base] = pack2bf(acc, accN);
    WhQ[base] = pack2bf(wh, whN);
#endif
  }
  if (k==0){
    float a = 0.f;
    const float* b2l = b2 + l*HD;
    for (int m=0;m<HD;m++) a = fmaf(b2l[m], wihl[i*HD+m], a);
    bv[l*H3 + i] = a;
  }
}

#if USE_DOT2
static __device__ __forceinline__ float edge_term(uint4 ua, uint4 ub, const uint32* wch, float t){
  t = dot2h(ua.x, wch[0], t); t = dot2h(ua.y, wch[1], t);
  t = dot2h(ua.z, wch[2], t); t = dot2h(ua.w, wch[3], t);
  t = dot2h(ub.x, wch[4], t); t = dot2h(ub.y, wch[5], t);
  t = dot2h(ub.z, wch[6], t); t = dot2h(ub.w, wch[7], t);
  return t;
}
#else
static __device__ __forceinline__ float edge_term(uint4 ua, uint4 ub, const float* wch, float t){
  uint32 us[8] = {ua.x,ua.y,ua.z,ua.w,ub.x,ub.y,ub.z,ub.w};
  #pragma unroll
  for (int k=0;k<8;k++){
    t = fmaf(bf_lo(us[k]), wch[2*k],   t);
    t = fmaf(bf_hi(us[k]), wch[2*k+1], t);
  }
  return t;
}
#endif

// tsum[n] = sum over CSR edges of relu(m1[n] + m2[col] + eattr[e]@W1c).
// SCALARIZED row (R11 win): wid/row_ptr/col_s/eattr_b wave-uniform -> SMEM path.
template<int PERM>
__global__ __launch_bounds__(256) void k_agg(const float* __restrict__ m1, const ushort16* __restrict__ m2b,
    const float* __restrict__ eattr, const ushort16* __restrict__ eattr_b, const float* __restrict__ w1c,
    const int* __restrict__ row_ptr, const int* __restrict__ col_s, const int* __restrict__ eid_s,
    float* __restrict__ tsum){
  int lane = threadIdx.x & 63;
  int wid_v = blockIdx.x*4 + (threadIdx.x>>6);
  int wid = __builtin_amdgcn_readfirstlane(wid_v);
  if (wid >= NN) return;
  float base = m1[(size_t)wid*HD + lane];
  int s     = __builtin_amdgcn_readfirstlane(row_ptr[wid]);
  int e_end = __builtin_amdgcn_readfirstlane(row_ptr[wid+1]);
  float ts0=0.f, ts1=0.f, ts2=0.f, ts3=0.f;
  int idx = s;
  if (PERM){
    const char* mb = (const char*)m2b;
    uint32 l2 = (uint32)lane * 2u;
#if USE_DOT2
    uint32 wch[8];
    #pragma unroll
    for (int k=0;k<8;k++) wch[k] = pack2h(w1c[(2*k)*HD + lane], w1c[(2*k+1)*HD + lane]);
#else
    float wch[ED];
    #pragma unroll
    for (int k=0;k<ED;k++) wch[k] = w1c[k*HD + lane];
#endif
    for (; idx + 8 <= e_end; idx += 8){
      int c0 = col_s[idx+0], c1 = col_s[idx+1], c2 = col_s[idx+2], c3 = col_s[idx+3];
      int c4 = col_s[idx+4], c5 = col_s[idx+5], c6 = col_s[idx+6], c7 = col_s[idx+7];
      unsigned short g0 = *(const unsigned short*)(mb + (uint32)c0 + l2);
      unsigned short g1 = *(const unsigned short*)(mb + (uint32)c1 + l2);
      unsigned short g2 = *(const unsigned short*)(mb + (uint32)c2 + l2);
      unsigned short g3 = *(const unsigned short*)(mb + (uint32)c3 + l2);
      unsigned short g4 = *(const unsigned short*)(mb + (uint32)c4 + l2);
      unsigned short g5 = *(const unsigned short*)(mb + (uint32)c5 + l2);
      unsigned short g6 = *(const unsigned short*)(mb + (uint32)c6 + l2);
      unsigned short g7 = *(const unsigned short*)(mb + (uint32)c7 + l2);
      const uint4* ea = (const uint4*)(eattr_b + (size_t)idx*ED);
      uint4 e0=ea[0],  e1=ea[1],  e2=ea[2],  e3=ea[3];
      uint4 e4=ea[4],  e5=ea[5],  e6=ea[6],  e7=ea[7];
      uint4 e8=ea[8],  e9=ea[9],  e10=ea[10],e11=ea[11];
      uint4 e12=ea[12],e13=ea[13],e14=ea[14],e15=ea[15];
      ts0 += fmaxf(edge_term(e0,  e1,  wch, base + bf_lo(g0)), 0.f);
      ts1 += fmaxf(edge_term(e2,  e3,  wch, base + bf_lo(g1)), 0.f);
      ts2 += fmaxf(edge_term(e4,  e5,  wch, base + bf_lo(g2)), 0.f);
      ts3 += fmaxf(edge_term(e6,  e7,  wch, base + bf_lo(g3)), 0.f);
      ts0 += fmaxf(edge_term(e8,  e9,  wch, base + bf_lo(g4)), 0.f);
      ts1 += fmaxf(edge_term(e10, e11, wch, base + bf_lo(g5)), 0.f);
      ts2 += fmaxf(edge_term(e12, e13, wch, base + bf_lo(g6)), 0.f);
      ts3 += fmaxf(edge_term(e14, e15, wch, base + bf_lo(g7)), 0.f);
    }
    if (idx + 4 <= e_end){
      int c0 = col_s[idx+0], c1 = col_s[idx+1], c2 = col_s[idx+2], c3 = col_s[idx+3];
      unsigned short g0 = *(const unsigned short*)(mb + (uint32)c0 + l2);
      unsigned short g1 = *(const unsigned short*)(mb + (uint32)c1 + l2);
      unsigned short g2 = *(const unsigned short*)(mb + (uint32)c2 + l2);
      unsigned short g3 = *(const unsigned short*)(mb + (uint32)c3 + l2);
      const uint4* ea = (const uint4*)(eattr_b + (size_t)idx*ED);
      uint4 e0=ea[0], e1=ea[1], e2=ea[2], e3=ea[3];
      uint4 e4=ea[4], e5=ea[5], e6=ea[6], e7=ea[7];
      ts0 += fmaxf(edge_term(e0, e1, wch, base + bf_lo(g0)), 0.f);
      ts1 += fmaxf(edge_term(e2, e3, wch, base + bf_lo(g1)), 0.f);
      ts2 += fmaxf(edge_term(e4, e5, wch, base + bf_lo(g2)), 0.f);
      ts3 += fmaxf(edge_term(e6, e7, wch, base + bf_lo(g3)), 0.f);
      idx += 4;
    }
    for (; idx < e_end; idx++){
      int c = col_s[idx];
      unsigned short g = *(const unsigned short*)(mb + (uint32)c + l2);
      const uint4* ea = (const uint4*)(eattr_b + (size_t)idx*ED);
      uint4 e0 = ea[0], e1 = ea[1];
      ts0 += fmaxf(edge_term(e0, e1, wch, base + bf_lo(g)), 0.f);
    }
  } else {
    float wc[ED];
    #pragma unroll
    for (int k=0;k<ED;k++) wc[k] = w1c[k*HD + lane];
    for (; idx < e_end; idx++){
      int c = col_s[idx];
      int e = eid_s[idx];
      const float4* ea4 = (const float4*)(eattr + (size_t)e*ED);
      float4 a0 = ea4[0], a1 = ea4[1], a2 = ea4[2], a3 = ea4[3];
      float t = base + bf_lo((uint32)m2b[(size_t)c*HD + lane]);
      t = fmaf(a0.x, wc[0],  t); t = fmaf(a0.y, wc[1],  t);
      t = fmaf(a0.z, wc[2],  t); t = fmaf(a0.w, wc[3],  t);
      t = fmaf(a1.x, wc[4],  t); t = fmaf(a1.y, wc[5],  t);
      t = fmaf(a1.z, wc[6],  t); t = fmaf(a1.w, wc[7],  t);
      t = fmaf(a2.x, wc[8],  t); t = fmaf(a2.y, wc[9],  t);
      t = fmaf(a2.z, wc[10], t); t = fmaf(a2.w, wc[11], t);
      t = fmaf(a3.x, wc[12], t); t = fmaf(a3.y, wc[13], t);
      t = fmaf(a3.z, wc[14], t); t = fmaf(a3.w, wc[15], t);
      ts0 += fmaxf(t, 0.f);
    }
  }
  tsum[(size_t)wid*HD + lane] = (ts0 + ts1) + (ts2 + ts3);
}

#if USE_DOT2
// GRU, 8 nodes/wave, dot2 inner loop (verified R17): acts f16-packed in
// wave-private LDS, weights f16-packed gate-interleaved uint4.
__global__ __launch_bounds__(256) void k_gru(float* __restrict__ h, const float* __restrict__ tsum,
    const int* __restrict__ row_ptr,
    const uint32* __restrict__ WfQ, const uint32* __restrict__ WhQ,
    const float* __restrict__ bv, const float* __restrict__ bih, const float* __restrict__ bhh){
  __shared__ uint32 tsP[4][8][32];  // 4 KB
  __shared__ uint32 hP[4][8][32];   // 4 KB
  int w4 = threadIdx.x >> 6, lane = threadIdx.x & 63;
  int nb = blockIdx.x*32 + w4*8;
  if (nb >= NN) return;
  {
    int n = lane>>3, j = lane&7;
    const float4* t4 = (const float4*)(tsum + (size_t)(nb+n)*HD + j*8);
    float4 a0=t4[0], a1=t4[1];
    uint4 pt;
    pt.x=pack2h(a0.x,a0.y); pt.y=pack2h(a0.z,a0.w); pt.z=pack2h(a1.x,a1.y); pt.w=pack2h(a1.z,a1.w);
    *(uint4*)&tsP[w4][n][j*4] = pt;
    const float4* g4 = (const float4*)(h + (size_t)(nb+n)*HD + j*8);
    float4 b0=g4[0], b1=g4[1];
    uint4 ph;
    ph.x=pack2h(b0.x,b0.y); ph.y=pack2h(b0.z,b0.w); ph.z=pack2h(b1.x,b1.y); ph.w=pack2h(b1.z,b1.w);
    *(uint4*)&hP[w4][n][j*4] = ph;
  }
  const uint4* fq = (const uint4*)WfQ;
  const uint4* hq = (const uint4*)WhQ;
  float gr[8]={0,0,0,0,0,0,0,0}, gz[8]={0,0,0,0,0,0,0,0}, gn[8]={0,0,0,0,0,0,0,0};
  float pr[8]={0,0,0,0,0,0,0,0}, pz[8]={0,0,0,0,0,0,0,0}, pn[8]={0,0,0,0,0,0,0,0};
  #pragma unroll 2
  for (int kq=0;kq<HD/4;kq++){
    uint4 f0 = fq[(2*kq)*64 + lane];
    uint4 f1 = fq[(2*kq+1)*64 + lane];
    uint4 h0 = hq[(2*kq)*64 + lane];
    uint4 h1 = hq[(2*kq+1)*64 + lane];
    #pragma unroll
    for (int n=0;n<8;n++){
      uint32 ta0 = tsP[w4][n][2*kq], ta1 = tsP[w4][n][2*kq+1];
      uint32 hb0 = hP[w4][n][2*kq],  hb1 = hP[w4][n][2*kq+1];
      gr[n]=dot2h(ta0,f0.x,gr[n]); gr[n]=dot2h(ta1,f1.x,gr[n]);
      gz[n]=dot2h(ta0,f0.y,gz[n]); gz[n]=dot2h(ta1,f1.y,gz[n]);
      gn[n]=dot2h(ta0,f0.z,gn[n]); gn[n]=dot2h(ta1,f1.z,gn[n]);
      pr[n]=dot2h(hb0,h0.x,pr[n]); pr[n]=dot2h(hb1,h1.x,pr[n]);
      pz[n]=dot2h(hb0,h0.y,pz[n]); pz[n]=dot2h(hb1,h1.y,pz[n]);
      pn[n]=dot2h(hb0,h0.z,pn[n]); pn[n]=dot2h(hb1,h1.z,pn[n]);
    }
  }
  float bvr=bv[lane], bvz=bv[HD+lane], bvn=bv[2*HD+lane];
  float bir=bih[lane], biz=bih[HD+lane], bin=bih[2*HD+lane];
  float bhr=bhh[lane], bhz=bhh[HD+lane], bhn=bhh[2*HD+lane];
  int rp0 = row_ptr[nb];
  #pragma unroll
  for (int n=0;n<8;n++){
    int rp1 = row_ptr[nb+n+1];
    float deg = (float)(rp1 - rp0);
    rp0 = rp1;
    float r  = sigm(gr[n]+pr[n] + deg*bvr + bir + bhr);
    float z  = sigm(gz[n]+pz[n] + deg*bvz + biz + bhz);
    // torch GRU: n = tanh(gi_n + r*gh_n); gi_n = gn + deg*bvn + bin; gh_n = pn + bhn
    float nv = tanhf(gn[n] + deg*bvn + bin + r*(pn[n] + bhn));
    float hv = h[(size_t)(nb+n)*HD + lane];   // exact fp32 h for the blend (L2-hot)
    h[(size_t)(nb+n)*HD + lane] = (1.f - z)*nv + z*hv;
  }
}
#else
// bf16-unpack fallback (verified R16 structure).
__global__ __launch_bounds__(256) void k_gru(float* __restrict__ h, const float* __restrict__ tsum,
    const int* __restrict__ row_ptr,
    const uint32* __restrict__ WfQ, const uint32* __restrict__ WhQ,
    const float* __restrict__ bv, const float* __restrict__ bih, const float* __restrict__ bhh){
  __shared__ float tsL[4][8][HD];
  __shared__ float hL[4][8][HD];
  int w4 = threadIdx.x >> 6, lane = threadIdx.x & 63;
  int nb = blockIdx.x*32 + w4*8;
  if (nb >= NN) return;
  #pragma unroll
  for (int n=0;n<8;n++){
    tsL[w4][n][lane] = tsum[(size_t)(nb+n)*HD + lane];
    hL[w4][n][lane]  = h[(size_t)(nb+n)*HD + lane];
  }
  const uint4* fq = (const uint4*)WfQ;
  const uint4* hq = (const uint4*)WhQ;
  float gr[8]={0,0,0,0,0,0,0,0}, gz[8]={0,0,0,0,0,0,0,0}, gn[8]={0,0,0,0,0,0,0,0};
  float pr[8]={0,0,0,0,0,0,0,0}, pz[8]={0,0,0,0,0,0,0,0}, pn[8]={0,0,0,0,0,0,0,0};
  #pragma unroll 2
  for (int kq=0;kq<HD/4;kq++){
    uint4 f0 = fq[(2*kq)*64 + lane];
    uint4 f1 = fq[(2*kq+1)*64 + lane];
    uint4 h0 = hq[(2*kq)*64 + lane];
    uint4 h1 = hq[(2*kq+1)*64 + lane];
    float wfr[4]={bf_lo(f0.x),bf_hi(f0.x),bf_lo(f1.x),bf_hi(f1.x)};
    float wfz[4]={bf_lo(f0.y),bf_hi(f0.y),bf_lo(f1.y),bf_hi(f1.y)};
    float wfn[4]={bf_lo(f0.z),bf_hi(f0.z),bf_lo(f1.z),bf_hi(f1.z)};
    float whr[4]={bf_lo(h0.x),bf_hi(h0.x),bf_lo(h1.x),bf_hi(h1.x)};
    float whz[4]={bf_lo(h0.y),bf_hi(h0.y),bf_lo(h1.y),bf_hi(h1.y)};
    float whn[4]={bf_lo(h0.z),bf_hi(h0.z),bf_lo(h1.z),bf_hi(h1.z)};
    #pragma unroll
    for (int n=0;n<8;n++){
      float tk[4], hk[4];
      *(float4*)tk = *(const float4*)&tsL[w4][n][kq*4];
      *(float4*)hk = *(const float4*)&hL[w4][n][kq*4];
      #pragma unroll
      for (int q=0;q<4;q++){
        gr[n]=fmaf(tk[q],wfr[q],gr[n]); gz[n]=fmaf(tk[q],wfz[q],gz[n]); gn[n]=fmaf(tk[q],wfn[q],gn[n]);
        pr[n]=fmaf(hk[q],whr[q],pr[n]); pz[n]=fmaf(hk[q],whz[q],pz[n]); pn[n]=fmaf(hk[q],whn[q],pn[n]);
      }
    }
  }
  float bvr=bv[lane], bvz=bv[HD+lane], bvn=bv[2*HD+lane];
  float bir=bih[lane], biz=bih[HD+lane], bin=bih[2*HD+lane];
  float bhr=bhh[lane], bhz=bhh[HD+lane], bhn=bhh[2*HD+lane];
  int rp0 = row_ptr[nb];
  #pragma unroll
  for (int n=0;n<8;n++){
    int rp1 = row_ptr[nb+n+1];
    float deg = (float)(rp1 - rp0);
    rp0 = rp1;
    float r  = sigm(gr[n]+pr[n] + deg*bvr + bir + bhr);
    float z  = sigm(gz[n]+pz[n] + deg*bvz + biz + bhz);
    float nv = tanhf(gn[n] + deg*bvn + bin + r*(pn[n] + bhn));
    float hv = hL[w4][n][lane];
    h[(size_t)(nb+n)*HD + lane] = (1.f - z)*nv + z*hv;
  }
}
#endif

// Graph-centric mean pool.
__global__ __launch_bounds__(256) void k_pool(const float* __restrict__ h, const int* __restrict__ batch,
    float* __restrict__ gsum, float* __restrict__ gcnt){
  __shared__ int rng[2];
  __shared__ float red[4][HD];
  int g = blockIdx.x / POOL_SLICES;
  int slice = blockIdx.x % POOL_SLICES;
  int t = threadIdx.x, lane = t & 63, w = t >> 6;
  if (t < 2){
    int target = g + t;
    int lo = 0, hi = NN;
    while (lo < hi){ int mid = (lo + hi) >> 1; if (batch[mid] < target) lo = mid + 1; else hi = mid; }
    rng[t] = lo;
  }
  __syncthreads();
  int start = rng[0], end = rng[1];
  if (slice == 0 && t == 0) gcnt[g] = (float)(end - start);
  int len = end - start;
  int per = (len + POOL_SLICES - 1) / POOL_SLICES;
  int s0 = start + slice * per;
  int s1 = min(s0 + per, end);
  float acc = 0.f;
  for (int n = s0 + w; n < s1; n += 4) acc += h[(size_t)n*HD + lane];
  red[w][lane] = acc;
  __syncthreads();
  if (w == 0){
    float v = red[0][lane] + red[1][lane] + red[2][lane] + red[3][lane];
    atomicAdd(&gsum[g*HD + lane], v);
  }
}

__global__ __launch_bounds__(64) void k_readout(const float* __restrict__ gsum, const float* __restrict__ gcnt,
    const float* __restrict__ w1, const float* __restrict__ b1,
    const float* __restrict__ w2, const float* __restrict__ b2, float* __restrict__ out){
  int g = blockIdx.x;
  int lane = threadIdx.x;
  float c = fmaxf(gcnt[g], 1.0f);
  float gm = gsum[g*HD + lane] / c;
  float a = b1[lane];
  for (int k=0;k<HD;k++) a = fmaf(__shfl(gm, k), w1[k*HD + lane], a);
  a = fmaxf(a, 0.f);
  float p = a * w2[lane];
  #pragma unroll
  for (int off=32; off>0; off>>=1) p += __shfl_down(p, off);
  if (lane==0) out[g] = 1.f/(1.f + expf(-(p + b2[0])));
}

extern "C" void kernel_launch(void* const* d_in, const int* in_sizes, int n_in,
                              void* d_out, int out_size, void* d_ws, size_t ws_size,
                              hipStream_t stream){
  const float* x        = (const float*)d_in[0];
  const int*   eidx     = (const int*)d_in[1];
  const float* eattr    = (const float*)d_in[2];
  const int*   batch    = (const int*)d_in[3];
  const float* emb_w    = (const float*)d_in[4];
  const float* emb_b    = (const float*)d_in[5];
  const float* msg_w1   = (const float*)d_in[6];
  const float* msg_b1   = (const float*)d_in[7];
  const float* msg_w2   = (const float*)d_in[8];
  const float* msg_b2   = (const float*)d_in[9];
  const float* gru_wih  = (const float*)d_in[10];
  const float* gru_whh  = (const float*)d_in[11];
  const float* gru_bih  = (const float*)d_in[12];
  const float* gru_bhh  = (const float*)d_in[13];
  const float* ro_w1    = (const float*)d_in[14];
  const float* ro_b1    = (const float*)d_in[15];
  const float* ro_w2    = (const float*)d_in[16];
  const float* ro_b2    = (const float*)d_in[17];
  float* out = (float*)d_out;

  char* p = (char*)d_ws;
  size_t used = 0;
  auto alloc = [&](size_t bytes)->void*{
    void* r = (void*)p; size_t rb = (bytes + 255) & ~(size_t)255; p += rb; used += rb; return r;
  };
  float*     h    = (float*)alloc((size_t)NN*HD*4);
  float*     m1   = (float*)alloc((size_t)NN*HD*4);
  ushort16*  m2b  = (ushort16*)alloc((size_t)NN*HD*2);
  float*     tsum = (float*)alloc((size_t)NN*HD*4);
  int*       deg  = (int*)  alloc((size_t)NN*4);
  int*       rowp = (int*)  alloc((size_t)(NN+1)*4);
  int*       rank = (int*)  alloc((size_t)NE*4);
  int*       col_s= (int*)  alloc((size_t)NE*4);
  int*       eid_s= (int*)  alloc((size_t)NE*4);
  uint32*    WfQ  = (uint32*)alloc((size_t)NL*32*64*4*4);  // gate-interleaved
  uint32*    WhQ  = (uint32*)alloc((size_t)NL*32*64*4*4);
  float*     bv   = (float*)alloc((size_t)NL*H3*4);
  float*     gsum = (float*)alloc((size_t)NG*HD*4);
  float*     gcnt = (float*)alloc((size_t)NG*4);
  // permuted f16/bf16 edge_attr (25.6 MB) — only if workspace allows
  size_t ea_bytes = (size_t)NE*ED*2;
  bool perm = (used + ea_bytes + 256) <= ws_size;
  ushort16* eattr_b = perm ? (ushort16*)alloc(ea_bytes) : nullptr;

  const int* row = eidx;
  const int* col = eidx + NE;

  hipMemsetAsync(deg,  0, (size_t)NN*4, stream);
  hipMemsetAsync(gsum, 0, (size_t)NG*HD*4, stream);

  const int nb32 = (NN + 31)/32;       // 8 nodes/wave, 4 waves/block
  const int nbw  = (NN + 3)/4;         // 1 node/wave (k_agg)
  const int nbe  = (NE + 255)/256;

  k_degree<<<nbe, 256, 0, stream>>>(row, deg, rank);
  k_scan  <<<1, 1024, 0, stream>>>(deg, rowp);
  if (perm) k_fill<1><<<nbe, 256, 0, stream>>>(row, col, rowp, rank, eattr, col_s, eid_s, eattr_b);
  else      k_fill<0><<<nbe, 256, 0, stream>>>(row, col, rowp, rank, eattr, col_s, eid_s, eattr_b);
  k_fold  <<<NL*H3, 64, 0, stream>>>(msg_w2, msg_b2, gru_wih, gru_whh, WfQ, WhQ, bv);
  k_embed_pre<<<nb32, 256, 0, stream>>>(x, emb_w, emb_b, msg_w1, msg_b1, h, m1, m2b);

  for (int l=0; l<NL; l++){
    const float* w1l = msg_w1 + (size_t)l*(2*HD+ED)*HD;
    if (l > 0){
      k_pre<<<nb32, 256, 0, stream>>>(h, w1l, msg_b1 + l*HD, m1, m2b);
    }
    if (perm) k_agg<1><<<nbw, 256, 0, stream>>>(m1, m2b, eattr, eattr_b, w1l + (size_t)2*HD*HD,
                                                rowp, col_s, eid_s, tsum);
    else      k_agg<0><<<nbw, 256, 0, stream>>>(m1, m2b, eattr, eattr_b, w1l + (size_t)2*HD*HD,
                                                rowp, col_s, eid_s, tsum);
    k_gru<<<nb32, 256, 0, stream>>>(h, tsum, rowp,
                                    WfQ + (size_t)l*32*64*4, WhQ + (size_t)l*32*64*4,
                                    bv + l*H3, gru_bih + l*H3, gru_bhh + l*H3);
  }

  k_pool   <<<NG*POOL_SLICES, 256, 0, stream>>>(h, batch, gsum, gcnt);
  k_readout<<<NG, 64, 0, stream>>>(gsum, gcnt, ro_w1, ro_b1, ro_w2, ro_b2, out);
}

// Round 21
// 436.135 us; speedup vs baseline: 1.1240x; 1.0012x over previous
//
#include <hip/hip_runtime.h>
#include <cstdint>

#define NN 50000
#define NE 800000
#define HD 64
#define ED 16
#define XD 128
#define NL 3
#define NG 64
#define H3 192
#define POOL_SLICES 16

typedef unsigned int uint32;
typedef unsigned short ushort16;

#if __has_builtin(__builtin_amdgcn_fdot2)
#define USE_DOT2 1
typedef _Float16 v2h __attribute__((ext_vector_type(2)));
#else
#define USE_DOT2 0
#endif

static __device__ __forceinline__ float sigm(float x){ return 1.0f/(1.0f+expf(-x)); }

static __device__ __forceinline__ uint32 f2bf_bits(float f){
  uint32 u = __float_as_uint(f);
  return (u + 0x7fffu + ((u>>16)&1u)) >> 16;
}
static __device__ __forceinline__ uint32 pack2bf(float a, float b){
  return f2bf_bits(a) | (f2bf_bits(b) << 16);
}
static __device__ __forceinline__ float bf_lo(uint32 u){ return __uint_as_float(u << 16); }
static __device__ __forceinline__ float bf_hi(uint32 u){ return __uint_as_float(u & 0xffff0000u); }

#if USE_DOT2
static __device__ __forceinline__ uint32 pack2h(float a, float b){
  v2h p = {(_Float16)a, (_Float16)b};
  return __builtin_bit_cast(uint32, p);
}
static __device__ __forceinline__ float dot2h(uint32 a, uint32 b, float c){
  return __builtin_amdgcn_fdot2(__builtin_bit_cast(v2h, a), __builtin_bit_cast(v2h, b), c, false);
}
#endif

// Shared pre-MLP epilogue: from a wave-local LDS copy of 8 node rows (stride ldh),
// compute m1 = h@W1a + b1 (fp32) and m2 = h@W1b (bf16). No block sync needed.
static __device__ __forceinline__ void pre_from_lds(const float* hW, int ldh,
    const float* __restrict__ w1, const float* __restrict__ b1,
    int nb, int lane, float* __restrict__ m1, ushort16* __restrict__ m2b){
  float a1[8] = {0,0,0,0,0,0,0,0};
  float a2[8] = {0,0,0,0,0,0,0,0};
  #pragma unroll 4
  for (int kq=0;kq<HD/4;kq++){
    float wa[4], wb[4];
    #pragma unroll
    for (int q=0;q<4;q++){
      wa[q] = w1[(kq*4+q)*HD + lane];
      wb[q] = w1[(HD+kq*4+q)*HD + lane];
    }
    #pragma unroll
    for (int n=0;n<8;n++){
      float hk[4];
      *(float4*)hk = *(const float4*)&hW[n*ldh + kq*4];
      #pragma unroll
      for (int q=0;q<4;q++){
        a1[n] = fmaf(hk[q], wa[q], a1[n]);
        a2[n] = fmaf(hk[q], wb[q], a2[n]);
      }
    }
  }
  float bb = b1[lane];
  #pragma unroll
  for (int n=0;n<8;n++){
    m1[(size_t)(nb+n)*HD + lane] = a1[n] + bb;
    m2b[(size_t)(nb+n)*HD + lane] = (ushort16)f2bf_bits(a2[n]);
  }
}

// Fused: h = x@emb_w + emb_b, then layer-0 pre (m1, m2b). Wave handles 8 nodes.
__global__ __launch_bounds__(256) void k_embed_pre(const float* __restrict__ x,
    const float* __restrict__ w, const float* __restrict__ b,
    const float* __restrict__ w1_0, const float* __restrict__ b1_0,
    float* __restrict__ h, float* __restrict__ m1, ushort16* __restrict__ m2b){
  __shared__ float xL[4][8][XD];   // 16 KB
  int w4 = threadIdx.x >> 6, lane = threadIdx.x & 63;
  int nb = blockIdx.x*32 + w4*8;
  if (nb >= NN) return;
  #pragma unroll
  for (int n=0;n<8;n++){
    xL[w4][n][lane]      = x[(size_t)(nb+n)*XD + lane];
    xL[w4][n][64+lane]   = x[(size_t)(nb+n)*XD + 64 + lane];
  }
  float a[8] = {0,0,0,0,0,0,0,0};
  #pragma unroll 4
  for (int kq=0;kq<XD/4;kq++){
    float wv[4];
    #pragma unroll
    for (int q=0;q<4;q++) wv[q] = w[(kq*4+q)*HD + lane];
    #pragma unroll
    for (int n=0;n<8;n++){
      float xk[4];
      *(float4*)xk = *(const float4*)&xL[w4][n][kq*4];
      #pragma unroll
      for (int q=0;q<4;q++) a[n] = fmaf(xk[q], wv[q], a[n]);
    }
  }
  float bb = b[lane];
  #pragma unroll
  for (int n=0;n<8;n++){
    float hv = a[n] + bb;
    h[(size_t)(nb+n)*HD + lane] = hv;
    xL[w4][n][lane] = hv;          // xL fully consumed; reuse first 64 cols as h
  }
  pre_from_lds(&xL[w4][0][0], XD, w1_0, b1_0, nb, lane, m1, m2b);
}

// Standalone pre (layers 1..L-1): h from global, staged in LDS.
__global__ __launch_bounds__(256) void k_pre(const float* __restrict__ h,
    const float* __restrict__ w1, const float* __restrict__ b1,
    float* __restrict__ m1, ushort16* __restrict__ m2b){
  __shared__ float hL[4][8][HD];   // 8 KB
  int w4 = threadIdx.x >> 6, lane = threadIdx.x & 63;
  int nb = blockIdx.x*32 + w4*8;
  if (nb >= NN) return;
  #pragma unroll
  for (int n=0;n<8;n++) hL[w4][n][lane] = h[(size_t)(nb+n)*HD + lane];
  pre_from_lds(&hL[w4][0][0], HD, w1, b1, nb, lane, m1, m2b);
}

// Degree + per-edge rank (coalesced 4B write by e): rank[e] = old count.
__global__ __launch_bounds__(256) void k_degree(const int* __restrict__ row,
    int* __restrict__ deg, int* __restrict__ rank){
  int e = blockIdx.x*blockDim.x + threadIdx.x;
  if (e < NE) rank[e] = atomicAdd(&deg[row[e]], 1);
}

// single-block exclusive scan over deg -> row_ptr[N+1]
__global__ __launch_bounds__(1024) void k_scan(const int* __restrict__ deg,
    int* __restrict__ row_ptr){
  __shared__ int wsum[16];
  __shared__ int wexcl[16];
  int t = threadIdx.x, lane = t & 63, wid = t >> 6;
  int running = 0;
  for (int base = 0; base < NN; base += 1024){
    int i = base + t;
    int v = (i < NN) ? deg[i] : 0;
    int s = v;
    #pragma unroll
    for (int off=1; off<64; off<<=1){ int u = __shfl_up(s, off); if (lane>=off) s += u; }
    if (lane==63) wsum[wid] = s;
    __syncthreads();
    if (wid==0){
      int ws = (lane<16) ? wsum[lane] : 0;
      #pragma unroll
      for (int off=1; off<16; off<<=1){ int u = __shfl_up(ws, off); if (lane>=off) ws += u; }
      if (lane<16) wexcl[lane] = ws - wsum[lane];
    }
    __syncthreads();
    int excl = running + wexcl[wid] + (s - v);
    if (i < NN) row_ptr[i] = excl;
    running += wexcl[15] + wsum[15];
    __syncthreads();
  }
  if (t==0) row_ptr[NN] = running;
}

// CSR fill, ATOMIC-FREE: p = row_ptr[row[e]] + rank[e] (plain loads). Single-
// pass payload scatter (R18 lesson: write amplification is 64B-line-granular).
template<int PERM>
__global__ __launch_bounds__(256) void k_fill(const int* __restrict__ row, const int* __restrict__ colv,
    const int* __restrict__ row_ptr, const int* __restrict__ rank,
    const float* __restrict__ eattr,
    int* __restrict__ col_s, int* __restrict__ eid_s,
    ushort16* __restrict__ eattr_b){
  int e = blockIdx.x*blockDim.x + threadIdx.x;
  if (e < NE){
    int r = row[e];
    int p = row_ptr[r] + rank[e];
    if (PERM){
      col_s[p] = colv[e] << 7;   // byte offset: col * HD * 2
      const float4* src = (const float4*)(eattr + (size_t)e*ED);
      float4 s0=src[0], s1=src[1], s2=src[2], s3=src[3];
      uint4 d0, d1;
#if USE_DOT2
      d0.x = pack2h(s0.x,s0.y); d0.y = pack2h(s0.z,s0.w);
      d0.z = pack2h(s1.x,s1.y); d0.w = pack2h(s1.z,s1.w);
      d1.x = pack2h(s2.x,s2.y); d1.y = pack2h(s2.z,s2.w);
      d1.z = pack2h(s3.x,s3.y); d1.w = pack2h(s3.z,s3.w);
#else
      d0.x = pack2bf(s0.x,s0.y); d0.y = pack2bf(s0.z,s0.w);
      d0.z = pack2bf(s1.x,s1.y); d0.w = pack2bf(s1.z,s1.w);
      d1.x = pack2bf(s2.x,s2.y); d1.y = pack2bf(s2.z,s2.w);
      d1.z = pack2bf(s3.x,s3.y); d1.w = pack2bf(s3.z,s3.w);
#endif
      uint4* dst = (uint4*)(eattr_b + (size_t)p*ED);
      dst[0] = d0; dst[1] = d1;
    } else {
      col_s[p] = colv[e];
      eid_s[p] = e;
    }
  }
}

// Fold + pack, GATE-INTERLEAVED layout: WfQ[l][kp][c][4] = {r-pair, z-pair,
// n-pair, pad}, pair packs (k=2kp, k=2kp+1).
__global__ __launch_bounds__(64) void k_fold(const float* __restrict__ w2, const float* __restrict__ b2,
    const float* __restrict__ wih, const float* __restrict__ whh,
    uint32* __restrict__ WfQ, uint32* __restrict__ WhQ, float* __restrict__ bv){
  int bid = blockIdx.x;
  int l = bid / H3, i = bid % H3;
  int k = threadIdx.x;
  const float* w2l  = w2  + (size_t)l*HD*HD;
  const float* wihl = wih + (size_t)l*H3*HD;
  const float* whhl = whh + (size_t)l*H3*HD;
  float acc = 0.f;
  #pragma unroll 8
  for (int m=0;m<HD;m++) acc = fmaf(w2l[k*HD+m], wihl[i*HD+m], acc);
  float wh = whhl[(size_t)i*HD + k];
  float accN = __shfl_down(acc, 1);
  float whN  = __shfl_down(wh, 1);
  if ((k & 1) == 0){
    int g = i >> 6, c = i & 63;
    size_t base = (((size_t)l*32 + (k>>1))*64 + c)*4 + g;
#if USE_DOT2
    WfQ[base] = pack2h(acc, accN);
    WhQ[base] = pack2h(wh, whN);
#else
    WfQ[base] = pack2bf(acc, accN);
    WhQ[base] = pack2bf(wh, whN);
#endif
  }
  if (k==0){
    float a = 0.f;
    const float* b2l = b2 + l*HD;
    for (int m=0;m<HD;m++) a = fmaf(b2l[m], wihl[i*HD+m], a);
    bv[l*H3 + i] = a;
  }
}

#if USE_DOT2
static __device__ __forceinline__ float edge_term(uint4 ua, uint4 ub, const uint32* wch, float t){
  t = dot2h(ua.x, wch[0], t); t = dot2h(ua.y, wch[1], t);
  t = dot2h(ua.z, wch[2], t); t = dot2h(ua.w, wch[3], t);
  t = dot2h(ub.x, wch[4], t); t = dot2h(ub.y, wch[5], t);
  t = dot2h(ub.z, wch[6], t); t = dot2h(ub.w, wch[7], t);
  return t;
}
#else
static __device__ __forceinline__ float edge_term(uint4 ua, uint4 ub, const float* wch, float t){
  uint32 us[8] = {ua.x,ua.y,ua.z,ua.w,ub.x,ub.y,ub.z,ub.w};
  #pragma unroll
  for (int k=0;k<8;k++){
    t = fmaf(bf_lo(us[k]), wch[2*k],   t);
    t = fmaf(bf_hi(us[k]), wch[2*k+1], t);
  }
  return t;
}
#endif

// tsum[n] = sum over CSR edges of relu(m1[n] + m2[col] + eattr[e]@W1c).
// SCALARIZED row (R11 win): wid/row_ptr/col_s/eattr_b wave-uniform -> SMEM path.
template<int PERM>
__global__ __launch_bounds__(256) void k_agg(const float* __restrict__ m1, const ushort16* __restrict__ m2b,
    const float* __restrict__ eattr, const ushort16* __restrict__ eattr_b, const float* __restrict__ w1c,
    const int* __restrict__ row_ptr, const int* __restrict__ col_s, const int* __restrict__ eid_s,
    float* __restrict__ tsum){
  int lane = threadIdx.x & 63;
  int wid_v = blockIdx.x*4 + (threadIdx.x>>6);
  int wid = __builtin_amdgcn_readfirstlane(wid_v);
  if (wid >= NN) return;
  float base = m1[(size_t)wid*HD + lane];
  int s     = __builtin_amdgcn_readfirstlane(row_ptr[wid]);
  int e_end = __builtin_amdgcn_readfirstlane(row_ptr[wid+1]);
  float ts0=0.f, ts1=0.f, ts2=0.f, ts3=0.f;
  int idx = s;
  if (PERM){
    const char* mb = (const char*)m2b;
    uint32 l2 = (uint32)lane * 2u;
#if USE_DOT2
    uint32 wch[8];
    #pragma unroll
    for (int k=0;k<8;k++) wch[k] = pack2h(w1c[(2*k)*HD + lane], w1c[(2*k+1)*HD + lane]);
#else
    float wch[ED];
    #pragma unroll
    for (int k=0;k<ED;k++) wch[k] = w1c[k*HD + lane];
#endif
    for (; idx + 8 <= e_end; idx += 8){
      int c0 = col_s[idx+0], c1 = col_s[idx+1], c2 = col_s[idx+2], c3 = col_s[idx+3];
      int c4 = col_s[idx+4], c5 = col_s[idx+5], c6 = col_s[idx+6], c7 = col_s[idx+7];
      unsigned short g0 = *(const unsigned short*)(mb + (uint32)c0 + l2);
      unsigned short g1 = *(const unsigned short*)(mb + (uint32)c1 + l2);
      unsigned short g2 = *(const unsigned short*)(mb + (uint32)c2 + l2);
      unsigned short g3 = *(const unsigned short*)(mb + (uint32)c3 + l2);
      unsigned short g4 = *(const unsigned short*)(mb + (uint32)c4 + l2);
      unsigned short g5 = *(const unsigned short*)(mb + (uint32)c5 + l2);
      unsigned short g6 = *(const unsigned short*)(mb + (uint32)c6 + l2);
      unsigned short g7 = *(const unsigned short*)(mb + (uint32)c7 + l2);
      const uint4* ea = (const uint4*)(eattr_b + (size_t)idx*ED);
      uint4 e0=ea[0],  e1=ea[1],  e2=ea[2],  e3=ea[3];
      uint4 e4=ea[4],  e5=ea[5],  e6=ea[6],  e7=ea[7];
      uint4 e8=ea[8],  e9=ea[9],  e10=ea[10],e11=ea[11];
      uint4 e12=ea[12],e13=ea[13],e14=ea[14],e15=ea[15];
      ts0 += fmaxf(edge_term(e0,  e1,  wch, base + bf_lo(g0)), 0.f);
      ts1 += fmaxf(edge_term(e2,  e3,  wch, base + bf_lo(g1)), 0.f);
      ts2 += fmaxf(edge_term(e4,  e5,  wch, base + bf_lo(g2)), 0.f);
      ts3 += fmaxf(edge_term(e6,  e7,  wch, base + bf_lo(g3)), 0.f);
      ts0 += fmaxf(edge_term(e8,  e9,  wch, base + bf_lo(g4)), 0.f);
      ts1 += fmaxf(edge_term(e10, e11, wch, base + bf_lo(g5)), 0.f);
      ts2 += fmaxf(edge_term(e12, e13, wch, base + bf_lo(g6)), 0.f);
      ts3 += fmaxf(edge_term(e14, e15, wch, base + bf_lo(g7)), 0.f);
    }
    if (idx + 4 <= e_end){
      int c0 = col_s[idx+0], c1 = col_s[idx+1], c2 = col_s[idx+2], c3 = col_s[idx+3];
      unsigned short g0 = *(const unsigned short*)(mb + (uint32)c0 + l2);
      unsigned short g1 = *(const unsigned short*)(mb + (uint32)c1 + l2);
      unsigned short g2 = *(const unsigned short*)(mb + (uint32)c2 + l2);
      unsigned short g3 = *(const unsigned short*)(mb + (uint32)c3 + l2);
      const uint4* ea = (const uint4*)(eattr_b + (size_t)idx*ED);
      uint4 e0=ea[0], e1=ea[1], e2=ea[2], e3=ea[3];
      uint4 e4=ea[4], e5=ea[5], e6=ea[6], e7=ea[7];
      ts0 += fmaxf(edge_term(e0, e1, wch, base + bf_lo(g0)), 0.f);
      ts1 += fmaxf(edge_term(e2, e3, wch, base + bf_lo(g1)), 0.f);
      ts2 += fmaxf(edge_term(e4, e5, wch, base + bf_lo(g2)), 0.f);
      ts3 += fmaxf(edge_term(e6, e7, wch, base + bf_lo(g3)), 0.f);
      idx += 4;
    }
    for (; idx < e_end; idx++){
      int c = col_s[idx];
      unsigned short g = *(const unsigned short*)(mb + (uint32)c + l2);
      const uint4* ea = (const uint4*)(eattr_b + (size_t)idx*ED);
      uint4 e0 = ea[0], e1 = ea[1];
      ts0 += fmaxf(edge_term(e0, e1, wch, base + bf_lo(g)), 0.f);
    }
  } else {
    float wc[ED];
    #pragma unroll
    for (int k=0;k<ED;k++) wc[k] = w1c[k*HD + lane];
    for (; idx < e_end; idx++){
      int c = col_s[idx];
      int e = eid_s[idx];
      const float4* ea4 = (const float4*)(eattr + (size_t)e*ED);
      float4 a0 = ea4[0], a1 = ea4[1], a2 = ea4[2], a3 = ea4[3];
      float t = base + bf_lo((uint32)m2b[(size_t)c*HD + lane]);
      t = fmaf(a0.x, wc[0],  t); t = fmaf(a0.y, wc[1],  t);
      t = fmaf(a0.z, wc[2],  t); t = fmaf(a0.w, wc[3],  t);
      t = fmaf(a1.x, wc[4],  t); t = fmaf(a1.y, wc[5],  t);
      t = fmaf(a1.z, wc[6],  t); t = fmaf(a1.w, wc[7],  t);
      t = fmaf(a2.x, wc[8],  t); t = fmaf(a2.y, wc[9],  t);
      t = fmaf(a2.z, wc[10], t); t = fmaf(a2.w, wc[11], t);
      t = fmaf(a3.x, wc[12], t); t = fmaf(a3.y, wc[13], t);
      t = fmaf(a3.z, wc[14], t); t = fmaf(a3.w, wc[15], t);
      ts0 += fmaxf(t, 0.f);
    }
  }
  tsum[(size_t)wid*HD + lane] = (ts0 + ts1) + (ts2 + ts3);
}

#if USE_DOT2
// GRU, 8 nodes/wave, dot2 inner loop (verified R17): acts f16-packed in
// wave-private LDS, weights f16-packed gate-interleaved uint4.
__global__ __launch_bounds__(256) void k_gru(float* __restrict__ h, const float* __restrict__ tsum,
    const int* __restrict__ row_ptr,
    const uint32* __restrict__ WfQ, const uint32* __restrict__ WhQ,
    const float* __restrict__ bv, const float* __restrict__ bih, const float* __restrict__ bhh){
  __shared__ uint32 tsP[4][8][32];  // 4 KB
  __shared__ uint32 hP[4][8][32];   // 4 KB
  int w4 = threadIdx.x >> 6, lane = threadIdx.x & 63;
  int nb = blockIdx.x*32 + w4*8;
  if (nb >= NN) return;
  {
    int n = lane>>3, j = lane&7;
    const float4* t4 = (const float4*)(tsum + (size_t)(nb+n)*HD + j*8);
    float4 a0=t4[0], a1=t4[1];
    uint4 pt;
    pt.x=pack2h(a0.x,a0.y); pt.y=pack2h(a0.z,a0.w); pt.z=pack2h(a1.x,a1.y); pt.w=pack2h(a1.z,a1.w);
    *(uint4*)&tsP[w4][n][j*4] = pt;
    const float4* g4 = (const float4*)(h + (size_t)(nb+n)*HD + j*8);
    float4 b0=g4[0], b1=g4[1];
    uint4 ph;
    ph.x=pack2h(b0.x,b0.y); ph.y=pack2h(b0.z,b0.w); ph.z=pack2h(b1.x,b1.y); ph.w=pack2h(b1.z,b1.w);
    *(uint4*)&hP[w4][n][j*4] = ph;
  }
  const uint4* fq = (const uint4*)WfQ;
  const uint4* hq = (const uint4*)WhQ;
  float gr[8]={0,0,0,0,0,0,0,0}, gz[8]={0,0,0,0,0,0,0,0}, gn[8]={0,0,0,0,0,0,0,0};
  float pr[8]={0,0,0,0,0,0,0,0}, pz[8]={0,0,0,0,0,0,0,0}, pn[8]={0,0,0,0,0,0,0,0};
  #pragma unroll 2
  for (int kq=0;kq<HD/4;kq++){
    uint4 f0 = fq[(2*kq)*64 + lane];
    uint4 f1 = fq[(2*kq+1)*64 + lane];
    uint4 h0 = hq[(2*kq)*64 + lane];
    uint4 h1 = hq[(2*kq+1)*64 + lane];
    #pragma unroll
    for (int n=0;n<8;n++){
      uint32 ta0 = tsP[w4][n][2*kq], ta1 = tsP[w4][n][2*kq+1];
      uint32 hb0 = hP[w4][n][2*kq],  hb1 = hP[w4][n][2*kq+1];
      gr[n]=dot2h(ta0,f0.x,gr[n]); gr[n]=dot2h(ta1,f1.x,gr[n]);
      gz[n]=dot2h(ta0,f0.y,gz[n]); gz[n]=dot2h(ta1,f1.y,gz[n]);
      gn[n]=dot2h(ta0,f0.z,gn[n]); gn[n]=dot2h(ta1,f1.z,gn[n]);
      pr[n]=dot2h(hb0,h0.x,pr[n]); pr[n]=dot2h(hb1,h1.x,pr[n]);
      pz[n]=dot2h(hb0,h0.y,pz[n]); pz[n]=dot2h(hb1,h1.y,pz[n]);
      pn[n]=dot2h(hb0,h0.z,pn[n]); pn[n]=dot2h(hb1,h1.z,pn[n]);
    }
  }
  float bvr=bv[lane], bvz=bv[HD+lane], bvn=bv[2*HD+lane];
  float bir=bih[lane], biz=bih[HD+lane], bin=bih[2*HD+lane];
  float bhr=bhh[lane], bhz=bhh[HD+lane], bhn=bhh[2*HD+lane];
  int rp0 = row_ptr[nb];
  #pragma unroll
  for (int n=0;n<8;n++){
    int rp1 = row_ptr[nb+n+1];
    float deg = (float)(rp1 - rp0);
    rp0 = rp1;
    float r  = sigm(gr[n]+pr[n] + deg*bvr + bir + bhr);
    float z  = sigm(gz[n]+pz[n] + deg*bvz + biz + bhz);
    // torch GRU: n = tanh(gi_n + r*gh_n); gi_n = gn + deg*bvn + bin; gh_n = pn + bhn
    float nv = tanhf(gn[n] + deg*bvn + bin + r*(pn[n] + bhn));
    float hv = h[(size_t)(nb+n)*HD + lane];   // exact fp32 h for the blend (L2-hot)
    h[(size_t)(nb+n)*HD + lane] = (1.f - z)*nv + z*hv;
  }
}
#else
// bf16-unpack fallback (verified R16 structure).
__global__ __launch_bounds__(256) void k_gru(float* __restrict__ h, const float* __restrict__ tsum,
    const int* __restrict__ row_ptr,
    const uint32* __restrict__ WfQ, const uint32* __restrict__ WhQ,
    const float* __restrict__ bv, const float* __restrict__ bih, const float* __restrict__ bhh){
  __shared__ float tsL[4][8][HD];
  __shared__ float hL[4][8][HD];
  int w4 = threadIdx.x >> 6, lane = threadIdx.x & 63;
  int nb = blockIdx.x*32 + w4*8;
  if (nb >= NN) return;
  #pragma unroll
  for (int n=0;n<8;n++){
    tsL[w4][n][lane] = tsum[(size_t)(nb+n)*HD + lane];
    hL[w4][n][lane]  = h[(size_t)(nb+n)*HD + lane];
  }
  const uint4* fq = (const uint4*)WfQ;
  const uint4* hq = (const uint4*)WhQ;
  float gr[8]={0,0,0,0,0,0,0,0}, gz[8]={0,0,0,0,0,0,0,0}, gn[8]={0,0,0,0,0,0,0,0};
  float pr[8]={0,0,0,0,0,0,0,0}, pz[8]={0,0,0,0,0,0,0,0}, pn[8]={0,0,0,0,0,0,0,0};
  #pragma unroll 2
  for (int kq=0;kq<HD/4;kq++){
    uint4 f0 = fq[(2*kq)*64 + lane];
    uint4 f1 = fq[(2*kq+1)*64 + lane];
    uint4 h0 = hq[(2*kq)*64 + lane];
    uint4 h1 = hq[(2*kq+1)*64 + lane];
    float wfr[4]={bf_lo(f0.x),bf_hi(f0.x),bf_lo(f1.x),bf_hi(f1.x)};
    float wfz[4]={bf_lo(f0.y),bf_hi(f0.y),bf_lo(f1.y),bf_hi(f1.y)};
    float wfn[4]={bf_lo(f0.z),bf_hi(f0.z),bf_lo(f1.z),bf_hi(f1.z)};
    float whr[4]={bf_lo(h0.x),bf_hi(h0.x),bf_lo(h1.x),bf_hi(h1.x)};
    float whz[4]={bf_lo(h0.y),bf_hi(h0.y),bf_lo(h1.y),bf_hi(h1.y)};
    float whn[4]={bf_lo(h0.z),bf_hi(h0.z),bf_lo(h1.z),bf_hi(h1.z)};
    #pragma unroll
    for (int n=0;n<8;n++){
      float tk[4], hk[4];
      *(float4*)tk = *(const float4*)&tsL[w4][n][kq*4];
      *(float4*)hk = *(const float4*)&hL[w4][n][kq*4];
      #pragma unroll
      for (int q=0;q<4;q++){
        gr[n]=fmaf(tk[q],wfr[q],gr[n]); gz[n]=fmaf(tk[q],wfz[q],gz[n]); gn[n]=fmaf(tk[q],wfn[q],gn[n]);
        pr[n]=fmaf(hk[q],whr[q],pr[n]); pz[n]=fmaf(hk[q],whz[q],pz[n]); pn[n]=fmaf(hk[q],whn[q],pn[n]);
      }
    }
  }
  float bvr=bv[lane], bvz=bv[HD+lane], bvn=bv[2*HD+lane];
  float bir=bih[lane], biz=bih[HD+lane], bin=bih[2*HD+lane];
  float bhr=bhh[lane], bhz=bhh[HD+lane], bhn=bhh[2*HD+lane];
  int rp0 = row_ptr[nb];
  #pragma unroll
  for (int n=0;n<8;n++){
    int rp1 = row_ptr[nb+n+1];
    float deg = (float)(rp1 - rp0);
    rp0 = rp1;
    float r  = sigm(gr[n]+pr[n] + deg*bvr + bir + bhr);
    float z  = sigm(gz[n]+pz[n] + deg*bvz + biz + bhz);
    float nv = tanhf(gn[n] + deg*bvn + bin + r*(pn[n] + bhn));
    float hv = hL[w4][n][lane];
    h[(size_t)(nb+n)*HD + lane] = (1.f - z)*nv + z*hv;
  }
}
#endif

// Graph-centric mean pool.
__global__ __launch_bounds__(256) void k_pool(const float* __restrict__ h, const int* __restrict__ batch,
    float* __restrict__ gsum, float* __restrict__ gcnt){
  __shared__ int rng[2];
  __shared__ float red[4][HD];
  int g = blockIdx.x / POOL_SLICES;
  int slice = blockIdx.x % POOL_SLICES;
  int t = threadIdx.x, lane = t & 63, w = t >> 6;
  if (t < 2){
    int target = g + t;
    int lo = 0, hi = NN;
    while (lo < hi){ int mid = (lo + hi) >> 1; if (batch[mid] < target) lo = mid + 1; else hi = mid; }
    rng[t] = lo;
  }
  __syncthreads();
  int start = rng[0], end = rng[1];
  if (slice == 0 && t == 0) gcnt[g] = (float)(end - start);
  int len = end - start;
  int per = (len + POOL_SLICES - 1) / POOL_SLICES;
  int s0 = start + slice * per;
  int s1 = min(s0 + per, end);
  float acc = 0.f;
  for (int n = s0 + w; n < s1; n += 4) acc += h[(size_t)n*HD + lane];
  red[w][lane] = acc;
  __syncthreads();
  if (w == 0){
    float v = red[0][lane] + red[1][lane] + red[2][lane] + red[3][lane];
    atomicAdd(&gsum[g*HD + lane], v);
  }
}

__global__ __launch_bounds__(64) void k_readout(const float* __restrict__ gsum, const float* __restrict__ gcnt,
    const float* __restrict__ w1, const float* __restrict__ b1,
    const float* __restrict__ w2, const float* __restrict__ b2, float* __restrict__ out){
  int g = blockIdx.x;
  int lane = threadIdx.x;
  float c = fmaxf(gcnt[g], 1.0f);
  float gm = gsum[g*HD + lane] / c;
  float a = b1[lane];
  for (int k=0;k<HD;k++) a = fmaf(__shfl(gm, k), w1[k*HD + lane], a);
  a = fmaxf(a, 0.f);
  float p = a * w2[lane];
  #pragma unroll
  for (int off=32; off>0; off>>=1) p += __shfl_down(p, off);
  if (lane==0) out[g] = 1.f/(1.f + expf(-(p + b2[0])));
}

extern "C" void kernel_launch(void* const* d_in, const int* in_sizes, int n_in,
                              void* d_out, int out_size, void* d_ws, size_t ws_size,
                              hipStream_t stream){
  const float* x        = (const float*)d_in[0];
  const int*   eidx     = (const int*)d_in[1];
  const float* eattr    = (const float*)d_in[2];
  const int*   batch    = (const int*)d_in[3];
  const float* emb_w    = (const float*)d_in[4];
  const float* emb_b    = (const float*)d_in[5];
  const float* msg_w1   = (const float*)d_in[6];
  const float* msg_b1   = (const float*)d_in[7];
  const float* msg_w2   = (const float*)d_in[8];
  const float* msg_b2   = (const float*)d_in[9];
  const float* gru_wih  = (const float*)d_in[10];
  const float* gru_whh  = (const float*)d_in[11];
  const float* gru_bih  = (const float*)d_in[12];
  const float* gru_bhh  = (const float*)d_in[13];
  const float* ro_w1    = (const float*)d_in[14];
  const float* ro_b1    = (const float*)d_in[15];
  const float* ro_w2    = (const float*)d_in[16];
  const float* ro_b2    = (const float*)d_in[17];
  float* out = (float*)d_out;

  char* p = (char*)d_ws;
  size_t used = 0;
  auto alloc = [&](size_t bytes)->void*{
    void* r = (void*)p; size_t rb = (bytes + 255) & ~(size_t)255; p += rb; used += rb; return r;
  };
  float*     h    = (float*)alloc((size_t)NN*HD*4);
  float*     m1   = (float*)alloc((size_t)NN*HD*4);
  ushort16*  m2b  = (ushort16*)alloc((size_t)NN*HD*2);
  float*     tsum = (float*)alloc((size_t)NN*HD*4);
  int*       deg  = (int*)  alloc((size_t)NN*4);
  int*       rowp = (int*)  alloc((size_t)(NN+1)*4);
  int*       rank = (int*)  alloc((size_t)NE*4);
  int*       col_s= (int*)  alloc((size_t)NE*4);
  int*       eid_s= (int*)  alloc((size_t)NE*4);
  uint32*    WfQ  = (uint32*)alloc((size_t)NL*32*64*4*4);  // gate-interleaved
  uint32*    WhQ  = (uint32*)alloc((size_t)NL*32*64*4*4);
  float*     bv   = (float*)alloc((size_t)NL*H3*4);
  float*     gsum = (float*)alloc((size_t)NG*HD*4);
  float*     gcnt = (float*)alloc((size_t)NG*4);
  // permuted f16/bf16 edge_attr (25.6 MB) — only if workspace allows
  size_t ea_bytes = (size_t)NE*ED*2;
  bool perm = (used + ea_bytes + 256) <= ws_size;
  ushort16* eattr_b = perm ? (ushort16*)alloc(ea_bytes) : nullptr;

  const int* row = eidx;
  const int* col = eidx + NE;

  hipMemsetAsync(deg,  0, (size_t)NN*4, stream);
  hipMemsetAsync(gsum, 0, (size_t)NG*HD*4, stream);

  const int nb32 = (NN + 31)/32;       // 8 nodes/wave, 4 waves/block
  const int nbw  = (NN + 3)/4;         // 1 node/wave (k_agg)
  const int nbe  = (NE + 255)/256;

  k_degree<<<nbe, 256, 0, stream>>>(row, deg, rank);
  k_scan  <<<1, 1024, 0, stream>>>(deg, rowp);
  if (perm) k_fill<1><<<nbe, 256, 0, stream>>>(row, col, rowp, rank, eattr, col_s, eid_s, eattr_b);
  else      k_fill<0><<<nbe, 256, 0, stream>>>(row, col, rowp, rank, eattr, col_s, eid_s, eattr_b);
  k_fold  <<<NL*H3, 64, 0, stream>>>(msg_w2, msg_b2, gru_wih, gru_whh, WfQ, WhQ, bv);
  k_embed_pre<<<nb32, 256, 0, stream>>>(x, emb_w, emb_b, msg_w1, msg_b1, h, m1, m2b);

  for (int l=0; l<NL; l++){
    const float* w1l = msg_w1 + (size_t)l*(2*HD+ED)*HD;
    if (l > 0){
      k_pre<<<nb32, 256, 0, stream>>>(h, w1l, msg_b1 + l*HD, m1, m2b);
    }
    if (perm) k_agg<1><<<nbw, 256, 0, stream>>>(m1, m2b, eattr, eattr_b, w1l + (size_t)2*HD*HD,
                                                rowp, col_s, eid_s, tsum);
    else      k_agg<0><<<nbw, 256, 0, stream>>>(m1, m2b, eattr, eattr_b, w1l + (size_t)2*HD*HD,
                                                rowp, col_s, eid_s, tsum);
    k_gru<<<nb32, 256, 0, stream>>>(h, tsum, rowp,
                                    WfQ + (size_t)l*32*64*4, WhQ + (size_t)l*32*64*4,
                                    bv + l*H3, gru_bih + l*H3, gru_bhh + l*H3);
  }

  k_pool   <<<NG*POOL_SLICES, 256, 0, stream>>>(h, batch, gsum, gcnt);
  k_readout<<<NG, 64, 0, stream>>>(gsum, gcnt, ro_w1, ro_b1, ro_w2, ro_b2, out);
}